// Round 3
// baseline (757.110 us; speedup 1.0000x reference)
//
#include <hip/hip_runtime.h>
#include <stdint.h>
#include <stddef.h>

// ---------------------------------------------------------------------------
// Gemma2AttentionWithExpert: fused two-stream QKV + RoPE + GQA attention +
// per-stream output projection.  All GEMMs via f16 MFMA (16x16x32), fp32 acc.
// B=4, L1=1024, L2=512, L=1536, D_PG=2304, D_EX=1024, H=8, HKV=4, DH=256.
// Round 7: gemm_pipe reworked for occupancy + pipeline depth:
//   - BK=32, TRIPLE-buffered LDS (3 x 24KB = 72KB) -> 2 blocks/CU resident
//     (launch_bounds(512,4)), inter-block TLP covers barrier drains.
//   - vmcnt(3) at loop top = 2-tile prefetch slack (~1200cy > 900cy HBM lat).
//   - bijective XCD-chunk swizzle on all GEMM grids (grid%8==0 everywhere).
// ---------------------------------------------------------------------------

typedef _Float16 f16;
typedef _Float16 f16x8 __attribute__((ext_vector_type(8)));
typedef _Float16 f16x4 __attribute__((ext_vector_type(4)));
typedef float    f32x4 __attribute__((ext_vector_type(4)));

__device__ __forceinline__ void async_ld16(const void* g, void* l) {
  __builtin_amdgcn_global_load_lds((const __attribute__((address_space(1))) void*)g,
                                   (__attribute__((address_space(3))) void*)l,
                                   16, 0, 0);
}

// bijective XCD-chunk swizzle; requires n % 8 == 0
__device__ __forceinline__ int xswz(int bid, int n) {
  return (bid & 7) * (n >> 3) + (bid >> 3);
}

// ---------------------------------------------------------------------------
// gemm_pipe: 256x128 output tile, A:[256,lda] rm, B:[128,ldb] rm (B^T layout),
// K%64==0, 512 threads = 8 waves (4M x 2N), wave tile 64x64.
// LDS 72KB = 3 tile-buffers x (A[256][32] 16KB + B[128][32] 8KB).
// Per K-tile(32): {vmcnt(3) | barrier | 8x ds_read_b128 | stage tile t+2
// (3x global_load_lds) | setprio(1) 16x MFMA setprio(0) | barrier}.
// ---------------------------------------------------------------------------
template <typename Epi>
__device__ __forceinline__ void gemm_pipe(f16* lds,
    const f16* __restrict__ A, int lda,
    const f16* __restrict__ B, int ldb,
    int K, Epi&& epi)
{
  const int t    = threadIdx.x;
  const int w    = t >> 6;
  const int lane = t & 63;
  const int q4   = lane >> 4;
  const int l16  = lane & 15;
  const int wm   = w >> 1;
  const int wn   = w & 1;

  // staging: wave w covers rows [w*16, w*16+16), 16B chunk (lane&3) of 64B row
  const int srow = w * 16 + (lane >> 2);
  const int scol = (lane & 3) * 8;
  const f16* aP = A + (size_t)srow * lda + scol;
  const f16* bP = B + (size_t)srow * ldb + scol;
  const size_t a128 = (size_t)128 * lda;
  const int wl = w * 512;             // per-wave 1KB LDS slice (f16 units)

  // fragment read bases within a buffer (f16 units)
  const int arow = (wm * 64 + l16) * 32 + q4 * 8;
  const int brow = (wn * 64 + l16) * 32 + q4 * 8;

  f32x4 acc[4][4];
  const f32x4 vz = {0.f, 0.f, 0.f, 0.f};
#pragma unroll
  for (int i = 0; i < 4; ++i)
#pragma unroll
    for (int j = 0; j < 4; ++j) acc[i][j] = vz;

  // buffer bi at lds + bi*12288: A rows 0-127 @0, rows 128-255 @4096, B @8192
#define STAGE3(kt, bi)                                            \
  { const int kk_ = (kt) << 5; f16* d_ = lds + (bi) * 12288;      \
    async_ld16(aP + kk_,        d_ + wl);                         \
    async_ld16(aP + a128 + kk_, d_ + 4096 + wl);                  \
    async_ld16(bP + kk_,        d_ + 8192 + wl); }

  // prologue: stage tiles 0 and 1 (6 loads in flight)
  STAGE3(0, 0);
  asm volatile("" ::: "memory");
  STAGE3(1, 1);

  const int NT = K >> 5;
  int cur = 0;
  for (int tk = 0; tk < NT; ++tk) {
    // retire tile tk's 3 loads (leave tk+1, tk+2 in flight)
    if (tk == NT - 1) asm volatile("s_waitcnt vmcnt(0)" ::: "memory");
    else              asm volatile("s_waitcnt vmcnt(3)" ::: "memory");
    asm volatile("s_barrier" ::: "memory");

    const f16* aS = lds + cur * 12288;
    const f16* bS = aS + 8192;
    f16x8 af[4], bf[4];
#pragma unroll
    for (int i = 0; i < 4; ++i) {
      af[i] = *(const f16x8*)(aS + arow + i * 512);
      bf[i] = *(const f16x8*)(bS + brow + i * 512);
    }
    if (tk + 2 < NT) {
      int nb = cur + 2; if (nb >= 3) nb -= 3;
      STAGE3(tk + 2, nb);
    }
    __builtin_amdgcn_s_setprio(1);
#pragma unroll
    for (int mi = 0; mi < 4; ++mi)
#pragma unroll
      for (int ni = 0; ni < 4; ++ni)
        acc[mi][ni] = __builtin_amdgcn_mfma_f32_16x16x32_f16(af[mi], bf[ni], acc[mi][ni], 0, 0, 0);
    __builtin_amdgcn_s_setprio(0);
    asm volatile("s_barrier" ::: "memory");
    ++cur; if (cur == 3) cur = 0;
  }
#undef STAGE3

  // C/D layout (m89-verified): row = quad*4 + reg, col = lane&15
#pragma unroll
  for (int mi = 0; mi < 4; ++mi)
#pragma unroll
    for (int ni = 0; ni < 4; ++ni)
#pragma unroll
      for (int r = 0; r < 4; ++r)
        epi(wm * 64 + mi * 16 + q4 * 4 + r, wn * 64 + ni * 16 + l16, acc[mi][ni][r]);
}

// ---------------------------------------------------------------------------
// k_qkv4: fused QKV, logical blocks [0,512): stream0 (K=2304); [512,768): s1
// ---------------------------------------------------------------------------
__global__ __launch_bounds__(512, 4) void k_qkv4(
    const f16* __restrict__ xpg, const f16* __restrict__ xex,
    const f16* __restrict__ W0,  const f16* __restrict__ W1,
    f16* __restrict__ q, f16* __restrict__ k, f16* __restrict__ v)
{
  __shared__ alignas(16) f16 lds[36864];
  const int idx = xswz(blockIdx.x, 768);
  int by, bx, K; const f16 *A, *B;
  const bool s0 = idx < 512;
  if (s0) { by = idx >> 5; bx = idx & 31; K = 2304;
            A = xpg + (size_t)by * 256 * 2304; B = W0 + (size_t)bx * 128 * 2304; }
  else    { int j = idx - 512; by = j >> 5; bx = j & 31; K = 1024;
            A = xex + (size_t)by * 256 * 1024; B = W1 + (size_t)bx * 128 * 1024; }

  f16* D; int ldd, coff;
  if (bx < 16)      { D = q; ldd = 2048; coff = 0; }
  else if (bx < 24) { D = k; ldd = 1024; coff = 2048; }
  else              { D = v; ldd = 1024; coff = 3072; }
  const int colb = bx * 128 - coff;
  const int rowb = s0 ? ((by >> 2) * 1536 + (by & 3) * 256)
                      : ((by >> 1) * 1536 + 1024 + (by & 1) * 256);

  gemm_pipe(lds, A, K, B, K, K, [&](int r, int c, float fv) {
    D[(size_t)(rowb + r) * ldd + colb + c] = (f16)fv;
  });
}

// ---- post pass: [0,6144) vtrans; [6144,15360) mask->f16; [15360,24576)
// in-place RoPE on pair-interleaved q/k (f16x8 = 4 pairs, float4 cos/sin) ----
__global__ __launch_bounds__(256) void k_post(
    f16* __restrict__ q, f16* __restrict__ k,
    const float* __restrict__ cs, const float* __restrict__ sn,
    const float* __restrict__ msk, f16* __restrict__ mkh,
    const f16* __restrict__ v, f16* __restrict__ vt)
{
  const int blk = blockIdx.x;
  if (blk < 6144) {
    // V transpose: v[B*1536,1024] -> vt[B][4][256][1536]
    __shared__ f16 tile[32][33];
    const int b = blk / 1536, r0 = blk % 1536;
    const int d0 = (r0 & 31) * 32, l0 = (r0 >> 5) * 32;
    const int t = threadIdx.x;
    const int tr = t >> 5, tc = t & 31;
#pragma unroll
    for (int i = 0; i < 4; ++i)
      tile[tr + i * 8][tc] = v[((size_t)b * 1536 + l0 + tr + i * 8) * 1024 + d0 + tc];
    __syncthreads();
#pragma unroll
    for (int i = 0; i < 4; ++i) {
      int d = d0 + tr + i * 8;
      vt[(((size_t)b * 4 + (d >> 8)) * 256 + (d & 255)) * 1536 + l0 + tc] = tile[tc][tr + i * 8];
    }
  } else if (blk < 15360) {
    const size_t gid = ((size_t)(blk - 6144) * 256 + threadIdx.x) * 4;
    float4 m4 = *(const float4*)(msk + gid);
    f16x4 o = {(f16)m4.x, (f16)m4.y, (f16)m4.z, (f16)m4.w};
    *(f16x4*)(mkh + gid) = o;
  } else {
    const size_t tid8 = ((size_t)(blk - 15360) * 256 + threadIdx.x) * 8;
    f16* base; size_t row; int col;
    if (tid8 < 12582912ull) { base = q + tid8; row = tid8 >> 11; col = (int)(tid8 & 2047); }
    else { size_t f = tid8 - 12582912ull; base = k + f; row = f >> 10; col = (int)(f & 1023); }
    const int j0 = (col & 255) >> 1;
    f16x8 x = *(const f16x8*)base;
    float4 c4 = *(const float4*)(cs + row * 128 + j0);
    float4 s4 = *(const float4*)(sn + row * 128 + j0);
    f16x8 o;
    const float cc[4] = {c4.x, c4.y, c4.z, c4.w};
    const float ss[4] = {s4.x, s4.y, s4.z, s4.w};
#pragma unroll
    for (int p = 0; p < 4; ++p) {
      float x1 = (float)x[2 * p], x2 = (float)x[2 * p + 1];
      o[2 * p]     = (f16)(x1 * cc[p] - x2 * ss[p]);
      o[2 * p + 1] = (f16)(x2 * cc[p] + x1 * ss[p]);
    }
    *(f16x8*)base = o;
  }
}

// ---------------------------------------------------------------------------
// k_attn3: unified attention mega-kernel on gemm_pipe (256x128 tiles).
//   logical blocks [0, nop): oproj batch b_op (72 out0 + 16 out1 = 88)
//   blocks [nop, nop+npv): PV batch b_pv reading Psrc (96)
//   blocks [nop+npv, ...): scores batch b_sc writing f16 Sdst (576)
// ---------------------------------------------------------------------------
__global__ __launch_bounds__(512, 4) void k_attn3(
    const f16* __restrict__ qb, const f16* __restrict__ kb,
    const f16* __restrict__ mask, f16* __restrict__ Sdst,
    const f16* __restrict__ Psrc, const f16* __restrict__ vt,
    f16* __restrict__ att0, f16* __restrict__ att1,
    const f16* __restrict__ wo0, const f16* __restrict__ wo1,
    float* __restrict__ out0, float* __restrict__ out1,
    int b_sc, int b_pv, int b_op, int npv, int nop)
{
  __shared__ alignas(16) f16 lds[36864];
  const int idx = xswz(blockIdx.x, (int)gridDim.x);
  if (idx < nop) {
    // output projection, K=2048
    int by, bx, ldc, rowb; const f16 *A, *B; float* C;
    if (idx < 72) { by = idx / 18; bx = idx % 18;
                    A = att0 + (size_t)(b_op * 4 + by) * 256 * 2048;
                    B = wo0 + (size_t)bx * 128 * 2048;
                    C = out0; ldc = 2304; rowb = b_op * 1024 + by * 256; }
    else          { int j = idx - 72; by = j >> 3; bx = j & 7;
                    A = att1 + (size_t)(b_op * 2 + by) * 256 * 2048;
                    B = wo1 + (size_t)bx * 128 * 2048;
                    C = out1; ldc = 1024; rowb = b_op * 512 + by * 256; }
    const int colb = bx * 128;
    gemm_pipe(lds, A, 2048, B, 2048, 2048, [&](int r, int c, float fv) {
      C[(size_t)(rowb + r) * ldc + colb + c] = fv;
    });
  } else if (idx < nop + npv) {
    // PV, K=1536
    const int j = idx - nop;
    const int h = j / 12, rem = j % 12, by = rem >> 1, bx = rem & 1;
    const f16* A = Psrc + (size_t)h * 1536 * 1536 + (size_t)by * 256 * 1536;
    const f16* B = vt + (size_t)(b_pv * 4 + (h >> 1)) * 256 * 1536 + (size_t)bx * 128 * 1536;
    f16* dst = (by < 4)
      ? att0 + (size_t)(b_pv * 1024 + by * 256) * 2048 + h * 256 + bx * 128
      : att1 + (size_t)(b_pv * 512 + (by - 4) * 256) * 2048 + h * 256 + bx * 128;
    gemm_pipe(lds, A, 1536, B, 1536, 1536, [&](int r, int c, float fv) {
      dst[(size_t)r * 2048 + c] = (f16)fv;
    });
  } else {
    // scores, K=256
    const int j = idx - nop - npv;
    const int h = j / 72, rem = j % 72, by = rem / 12, bx = rem % 12;
    const f16* A = qb + (size_t)b_sc * 1536 * 2048 + h * 256 + (size_t)by * 256 * 2048;
    const f16* B = kb + (size_t)b_sc * 1536 * 1024 + (h >> 1) * 256 + (size_t)bx * 128 * 1024;
    f16* Sz = Sdst + (size_t)h * 1536 * 1536 + (size_t)by * 256 * 1536 + bx * 128;
    const f16* mb = mask + (size_t)b_sc * 1536 * 1536 + (size_t)by * 256 * 1536 + bx * 128;
    gemm_pipe(lds, A, 2048, B, 1024, 256, [&](int r, int c, float fv) {
      size_t i = (size_t)r * 1536 + c;
      Sz[i] = (f16)(fv * 0.0625f + (float)mb[i]);
    });
  }
}

// ---- wave-per-row softmax over 1536, f16 in/out, in place ------------------
__global__ __launch_bounds__(256) void k_softmax(f16* __restrict__ S)
{
  const int row = blockIdx.x * 4 + (threadIdx.x >> 6);
  const int lane = threadIdx.x & 63;
  f16* p = S + (size_t)row * 1536 + lane * 8;
  f16x8 v0 = *(const f16x8*)p;
  f16x8 v1 = *(const f16x8*)(p + 512);
  f16x8 v2 = *(const f16x8*)(p + 1024);
  float x[24];
#pragma unroll
  for (int i = 0; i < 8; ++i) {
    x[i] = (float)v0[i]; x[8 + i] = (float)v1[i]; x[16 + i] = (float)v2[i];
  }
  float mx = x[0];
#pragma unroll
  for (int i = 1; i < 24; ++i) mx = fmaxf(mx, x[i]);
#pragma unroll
  for (int o = 32; o > 0; o >>= 1) mx = fmaxf(mx, __shfl_xor(mx, o, 64));
  float s = 0.f;
#pragma unroll
  for (int i = 0; i < 24; ++i) { x[i] = __expf(x[i] - mx); s += x[i]; }
#pragma unroll
  for (int o = 32; o > 0; o >>= 1) s += __shfl_xor(s, o, 64);
  const float inv = 1.f / s;
  f16x8 o0, o1, o2;
#pragma unroll
  for (int i = 0; i < 8; ++i) {
    o0[i] = (f16)(x[i] * inv); o1[i] = (f16)(x[8 + i] * inv); o2[i] = (f16)(x[16 + i] * inv);
  }
  *(f16x8*)p = o0; *(f16x8*)(p + 512) = o1; *(f16x8*)(p + 1024) = o2;
}

// ---- flat cast fp32->f16 (pg, ex, Wv0, Wo0, Wv1, Wo1) ----------------------
__global__ __launch_bounds__(256) void k_cast_all(
    const float* __restrict__ s0, const float* __restrict__ s1,
    const float* __restrict__ s2, const float* __restrict__ s3,
    const float* __restrict__ s4, const float* __restrict__ s5,
    f16* __restrict__ ws)
{
  const size_t gid = ((size_t)blockIdx.x * 256 + threadIdx.x) * 4;
  const float* s; size_t off, dst;
  if      (gid < 9437184ull)  { s = s0; off = gid;               dst = 0ull        + off; }
  else if (gid < 11534336ull) { s = s1; off = gid - 9437184ull;  dst = 9437184ull  + off; }
  else if (gid < 13893632ull) { s = s2; off = gid - 11534336ull; dst = 18612224ull + off; }
  else if (gid < 18612224ull) { s = s3; off = gid - 13893632ull; dst = 20971520ull + off; }
  else if (gid < 19660800ull) { s = s4; off = gid - 18612224ull; dst = 28835840ull + off; }
  else                        { s = s5; off = gid - 19660800ull; dst = 29884416ull + off; }
  float4 v = *(const float4*)(s + off);
  f16x4 o = {(f16)v.x, (f16)v.y, (f16)v.z, (f16)v.w};
  *(f16x4*)(ws + dst) = o;
}

// ---- Wq/Wk cast with per-head RoPE pair interleave: dst row h*256+w reads
// src row h*256 + (w>>1) + 128*(w&1).  One block per dst row. ---------------
__global__ __launch_bounds__(256) void k_cast_wr(
    const float* __restrict__ wq0, const float* __restrict__ wk0,
    const float* __restrict__ wq1, const float* __restrict__ wk1,
    f16* __restrict__ W0c, f16* __restrict__ W1c)
{
  const int idx = blockIdx.x;
  const float* src; f16* dstm; int K, r, drow;
  if      (idx < 2048) { src = wq0; dstm = W0c; K = 2304; r = idx;        drow = idx; }
  else if (idx < 3072) { src = wk0; dstm = W0c; K = 2304; r = idx - 2048; drow = idx; }
  else if (idx < 5120) { src = wq1; dstm = W1c; K = 1024; r = idx - 3072; drow = idx - 3072; }
  else                 { src = wk1; dstm = W1c; K = 1024; r = idx - 5120; drow = idx - 3072; }
  const int w = r & 255;
  const int srow = (r & ~255) + (w >> 1) + ((w & 1) << 7);
  const float* sp = src + (size_t)srow * K;
  f16* dp = dstm + (size_t)drow * K;
  for (int c = threadIdx.x * 4; c < K; c += 1024) {
    float4 v = *(const float4*)(sp + c);
    f16x4 o = {(f16)v.x, (f16)v.y, (f16)v.z, (f16)v.w};
    *(f16x4*)(dp + c) = o;
  }
}

// ---------------------------------------------------------------------------
extern "C" void kernel_launch(void* const* d_in, const int* in_sizes, int n_in,
                              void* d_out, int out_size, void* d_ws, size_t ws_size,
                              hipStream_t stream)
{
  (void)in_sizes; (void)n_in; (void)out_size; (void)ws_size;
  const float* pg  = (const float*)d_in[0];
  const float* ex  = (const float*)d_in[1];
  const float* cs  = (const float*)d_in[2];
  const float* sn  = (const float*)d_in[3];
  const float* msk = (const float*)d_in[4];

  char* ws = (char*)d_ws;
  f16* xpg  = (f16*)(ws + 0);           // [4096,2304]   (dead after qkv)
  f16* xex  = (f16*)(ws + 18874368);    // [2048,1024]   (dead after qkv)
  f16* W0c  = (f16*)(ws + 23068672);    // [4096,2304] Wq0i;Wk0i;Wv0 (dead after qkv)
  f16* wo0c = (f16*)(ws + 41943040);    // [2304,2048]
  f16* W1c  = (f16*)(ws + 51380224);    // [4096,1024] Wq1i;Wk1i;Wv1 (dead after qkv)
  f16* wo1c = (f16*)(ws + 59768832);    // [1024,2048]
  f16* qb   = (f16*)(ws + 63963136);    // [B*1536, 2048] f16, pair-interleaved
  f16* kb   = (f16*)(ws + 89128960);    // [B*1536, 1024]
  f16* vb   = (f16*)(ws + 101711872);   // [B*1536, 1024] (dead after post)
  f16* vt   = (f16*)(ws + 114294784);   // [B,4,256,1536]
  f16* att0 = (f16*)(ws + 126877696);   // [B*1024, 2048]
  f16* att1 = (f16*)(ws + 143654912);   // [B*512, 2048]
  f16* S0   = (f16*)(ws + 152043520);   // f16 S/P chunk A: 8*1536*1536
  f16* S1   = (f16*)(ws + 189792256);   // f16 S/P chunk B (ends 227,540,992)
  f16* mkh  = W0c;                      // f16 mask overlays dead W0c (18.9MB)
  float* out0 = (float*)d_out;          // [4,1024,2304]
  float* out1 = out0 + 9437184;         // [4,512,1024]

  // 1) casts
  k_cast_all<<<21248, 256, 0, stream>>>(
      pg, ex, (const float*)d_in[7], (const float*)d_in[8],
      (const float*)d_in[11], (const float*)d_in[12], (f16*)ws);
  k_cast_wr<<<6144, 256, 0, stream>>>(
      (const float*)d_in[5], (const float*)d_in[6],
      (const float*)d_in[9], (const float*)d_in[10], W0c, W1c);

  // 2) fused QKV (both streams) — BK=32 triple-buffered pipelined GEMM
  k_qkv4<<<768, 512, 0, stream>>>(xpg, xex, W0c, W1c, qb, kb, vb);

  // 3) merged post pass: vtrans + mask->f16 + in-place RoPE
  k_post<<<24576, 256, 0, stream>>>(qb, kb, cs, sn, msk, mkh, vb, vt);

  // 4) attention pipeline (double-buffered f16 S chunks); oproj(b) rides in
  //    the scores(b+2) launch.  Per batch: nop=88, npv=96, nsc=576.
  k_attn3<<<576, 512, 0, stream>>>(qb, kb, mkh, S0, S0, vt, att0, att1, wo0c, wo1c, out0, out1, 0, 0, 0, 0, 0);
  k_softmax<<<3072, 256, 0, stream>>>(S0);
  k_attn3<<<672, 512, 0, stream>>>(qb, kb, mkh, S1, S0, vt, att0, att1, wo0c, wo1c, out0, out1, 1, 0, 0, 96, 0);
  k_softmax<<<3072, 256, 0, stream>>>(S1);
  k_attn3<<<760, 512, 0, stream>>>(qb, kb, mkh, S0, S1, vt, att0, att1, wo0c, wo1c, out0, out1, 2, 1, 0, 96, 88);
  k_softmax<<<3072, 256, 0, stream>>>(S0);
  k_attn3<<<760, 512, 0, stream>>>(qb, kb, mkh, S1, S0, vt, att0, att1, wo0c, wo1c, out0, out1, 3, 2, 1, 96, 88);
  k_softmax<<<3072, 256, 0, stream>>>(S1);

  // 5) tail: PV b3 + oproj b2 (184), then oproj b3 (88)
  k_attn3<<<184, 512, 0, stream>>>(qb, kb, mkh, S0, S1, vt, att0, att1, wo0c, wo1c, out0, out1, 0, 3, 2, 96, 88);
  k_attn3<<<88, 512, 0, stream>>>(qb, kb, mkh, S0, S1, vt, att0, att1, wo0c, wo1c, out0, out1, 0, 0, 3, 0, 88);
}

// Round 4
// 682.221 us; speedup vs baseline: 1.1098x; 1.1098x over previous
//
#include <hip/hip_runtime.h>
#include <stdint.h>
#include <stddef.h>

// ---------------------------------------------------------------------------
// Gemma2AttentionWithExpert: fused two-stream QKV + RoPE + GQA attention +
// per-stream output projection.  All GEMMs via f16 MFMA (16x16x32), fp32 acc.
// B=4, L1=1024, L2=512, L=1536, D_PG=2304, D_EX=1024, H=8, HKV=4, DH=256.
// Round 8: 256x256 tile GEMM core (m201 geometry) for arithmetic intensity:
//   - 8 waves (2M x 4N), wave tile 128x64, acc 8x4 fragments.
//   - LDS 128KB: A/B double-buffered, [2ksub][256][32] f16 per buffer
//     (64B rows = bank-minimal for b128 fragment reads).
//   - per K-tile (BK=64): 2 phases {vmcnt(4) | barrier | 12 ds_read_b128 |
//     4 global_load_lds for t+1 | setprio(1) 32 MFMA setprio(0) | barrier}.
//   - 1 block/CU, launch_bounds(512,2).  No XCD swizzle (R3 regression).
// ---------------------------------------------------------------------------

typedef _Float16 f16;
typedef _Float16 f16x8 __attribute__((ext_vector_type(8)));
typedef _Float16 f16x4 __attribute__((ext_vector_type(4)));
typedef float    f32x4 __attribute__((ext_vector_type(4)));

__device__ __forceinline__ void async_ld16(const void* g, void* l) {
  __builtin_amdgcn_global_load_lds((const __attribute__((address_space(1))) void*)g,
                                   (__attribute__((address_space(3))) void*)l,
                                   16, 0, 0);
}

// ---------------------------------------------------------------------------
// gemm256: 256x256 output tile, A:[256,lda] rm, B:[256,ldb] rm (B^T layout),
// K % 64 == 0.  512 threads = 8 waves (2M x 4N), wave tile 128x64.
// ---------------------------------------------------------------------------
template <typename Epi>
__device__ __forceinline__ void gemm256(f16* lds,
    const f16* __restrict__ A, int lda,
    const f16* __restrict__ B, int ldb,
    int K, Epi&& epi)
{
  const int t    = threadIdx.x;
  const int w    = t >> 6;
  const int lane = t & 63;
  const int q4   = lane >> 4;
  const int l16  = lane & 15;
  const int wm   = w >> 2;      // 0..1
  const int wn   = w & 3;       // 0..3

  f16* ldsA = lds;              // 2 buf x [2 ksub][256][32] f16 (64KB)
  f16* ldsB = lds + 32768;      // same (64KB)

  // staging: lane covers row (lane>>2) of a 16-row group, 16B chunk (lane&3)
  const f16* aP = A + (size_t)(lane >> 2) * lda + (lane & 3) * 8;
  const f16* bP = B + (size_t)(lane >> 2) * ldb + (lane & 3) * 8;
  const size_t aR0 = (size_t)(w * 32) * lda;        // wave's rowgroup 2w
  const size_t aR1 = aR0 + (size_t)16 * lda;        // rowgroup 2w+1
  const size_t bR0 = (size_t)(w * 32) * ldb;
  const size_t bR1 = bR0 + (size_t)16 * ldb;
  const int wo = w * 1024;      // dest f16 offset of wave's 2 rowgroups (2KB)

  // fragment read bases within a [256][32] ksub section (f16 units)
  const int arow = (wm * 128 + l16) * 32 + q4 * 8;
  const int brow = (wn * 64 + l16) * 32 + q4 * 8;

  f32x4 acc[8][4];
  const f32x4 vz = {0.f, 0.f, 0.f, 0.f};
#pragma unroll
  for (int i = 0; i < 8; ++i)
#pragma unroll
    for (int j = 0; j < 4; ++j) acc[i][j] = vz;

  // prologue: stage tile 0 (ksub0's 4 loads first, then ksub1's 4)
#pragma unroll
  for (int s = 0; s < 2; ++s) {
    const int kk = s * 32;
    async_ld16(aP + aR0 + kk, ldsA + s * 8192 + wo);
    async_ld16(aP + aR1 + kk, ldsA + s * 8192 + wo + 512);
    async_ld16(bP + bR0 + kk, ldsB + s * 8192 + wo);
    async_ld16(bP + bR1 + kk, ldsB + s * 8192 + wo + 512);
  }

  const int NT = K >> 6;
  for (int tk = 0; tk < NT; ++tk) {
    const int d  = (tk & 1) ? 16384 : 0;
    const int dn = 16384 - d;
    const bool st = tk + 1 < NT;
    const int kn = (tk + 1) << 6;
#pragma unroll
    for (int s = 0; s < 2; ++s) {
      // retire the 4 oldest loads (= ksub s of tile tk); keep 4 in flight
      if (s == 0 || st) asm volatile("s_waitcnt vmcnt(4)" ::: "memory");
      else              asm volatile("s_waitcnt vmcnt(0)" ::: "memory");
      asm volatile("s_barrier" ::: "memory");
      const f16* aS = ldsA + d + s * 8192;
      const f16* bS = ldsB + d + s * 8192;
      f16x8 af[8], bf[4];
#pragma unroll
      for (int i = 0; i < 8; ++i) af[i] = *(const f16x8*)(aS + arow + i * 512);
#pragma unroll
      for (int i = 0; i < 4; ++i) bf[i] = *(const f16x8*)(bS + brow + i * 512);
      if (st) {
        const int kk = kn + s * 32;
        async_ld16(aP + aR0 + kk, ldsA + dn + s * 8192 + wo);
        async_ld16(aP + aR1 + kk, ldsA + dn + s * 8192 + wo + 512);
        async_ld16(bP + bR0 + kk, ldsB + dn + s * 8192 + wo);
        async_ld16(bP + bR1 + kk, ldsB + dn + s * 8192 + wo + 512);
      }
      __builtin_amdgcn_s_setprio(1);
#pragma unroll
      for (int mi = 0; mi < 8; ++mi)
#pragma unroll
        for (int ni = 0; ni < 4; ++ni)
          acc[mi][ni] = __builtin_amdgcn_mfma_f32_16x16x32_f16(af[mi], bf[ni], acc[mi][ni], 0, 0, 0);
      __builtin_amdgcn_s_setprio(0);
      asm volatile("s_barrier" ::: "memory");
    }
  }

  // C/D layout (m89-verified): row = quad*4 + reg, col = lane&15
#pragma unroll
  for (int mi = 0; mi < 8; ++mi)
#pragma unroll
    for (int ni = 0; ni < 4; ++ni)
#pragma unroll
      for (int r = 0; r < 4; ++r)
        epi(wm * 128 + mi * 16 + q4 * 4 + r, wn * 64 + ni * 16 + l16, acc[mi][ni][r]);
}

// ---------------------------------------------------------------------------
// k_qkv5: fused QKV.  blocks [0,256): stream0 (16x16 tiles, K=2304);
// [256,384): stream1 (8x16 tiles, K=1024).  N-tiles of 256: bx<8 q, 8-11 k,
// 12-15 v (boundaries at 2048/3072 are multiples of 256).
// ---------------------------------------------------------------------------
__global__ __launch_bounds__(512, 2) void k_qkv5(
    const f16* __restrict__ xpg, const f16* __restrict__ xex,
    const f16* __restrict__ W0,  const f16* __restrict__ W1,
    f16* __restrict__ q, f16* __restrict__ k, f16* __restrict__ v)
{
  __shared__ alignas(16) f16 lds[65536];
  const int idx = blockIdx.x;
  int by, bx, K; const f16 *A, *B;
  const bool s0 = idx < 256;
  if (s0) { by = idx >> 4; bx = idx & 15; K = 2304;
            A = xpg + (size_t)by * 256 * 2304; B = W0 + (size_t)bx * 256 * 2304; }
  else    { int j = idx - 256; by = j >> 4; bx = j & 15; K = 1024;
            A = xex + (size_t)by * 256 * 1024; B = W1 + (size_t)bx * 256 * 1024; }

  f16* D; int ldd, coff;
  if (bx < 8)       { D = q; ldd = 2048; coff = 0; }
  else if (bx < 12) { D = k; ldd = 1024; coff = 2048; }
  else              { D = v; ldd = 1024; coff = 3072; }
  const int colb = bx * 256 - coff;
  const int rowb = s0 ? ((by >> 2) * 1536 + (by & 3) * 256)
                      : ((by >> 1) * 1536 + 1024 + (by & 1) * 256);

  gemm256(lds, A, K, B, K, K, [&](int r, int c, float fv) {
    D[(size_t)(rowb + r) * ldd + colb + c] = (f16)fv;
  });
}

// ---- post pass: [0,6144) vtrans; [6144,15360) mask->f16; [15360,24576)
// in-place RoPE on pair-interleaved q/k (f16x8 = 4 pairs, float4 cos/sin) ----
__global__ __launch_bounds__(256) void k_post(
    f16* __restrict__ q, f16* __restrict__ k,
    const float* __restrict__ cs, const float* __restrict__ sn,
    const float* __restrict__ msk, f16* __restrict__ mkh,
    const f16* __restrict__ v, f16* __restrict__ vt)
{
  const int blk = blockIdx.x;
  if (blk < 6144) {
    // V transpose: v[B*1536,1024] -> vt[B][4][256][1536]
    __shared__ f16 tile[32][33];
    const int b = blk / 1536, r0 = blk % 1536;
    const int d0 = (r0 & 31) * 32, l0 = (r0 >> 5) * 32;
    const int t = threadIdx.x;
    const int tr = t >> 5, tc = t & 31;
#pragma unroll
    for (int i = 0; i < 4; ++i)
      tile[tr + i * 8][tc] = v[((size_t)b * 1536 + l0 + tr + i * 8) * 1024 + d0 + tc];
    __syncthreads();
#pragma unroll
    for (int i = 0; i < 4; ++i) {
      int d = d0 + tr + i * 8;
      vt[(((size_t)b * 4 + (d >> 8)) * 256 + (d & 255)) * 1536 + l0 + tc] = tile[tc][tr + i * 8];
    }
  } else if (blk < 15360) {
    const size_t gid = ((size_t)(blk - 6144) * 256 + threadIdx.x) * 4;
    float4 m4 = *(const float4*)(msk + gid);
    f16x4 o = {(f16)m4.x, (f16)m4.y, (f16)m4.z, (f16)m4.w};
    *(f16x4*)(mkh + gid) = o;
  } else {
    const size_t tid8 = ((size_t)(blk - 15360) * 256 + threadIdx.x) * 8;
    f16* base; size_t row; int col;
    if (tid8 < 12582912ull) { base = q + tid8; row = tid8 >> 11; col = (int)(tid8 & 2047); }
    else { size_t f = tid8 - 12582912ull; base = k + f; row = f >> 10; col = (int)(f & 1023); }
    const int j0 = (col & 255) >> 1;
    f16x8 x = *(const f16x8*)base;
    float4 c4 = *(const float4*)(cs + row * 128 + j0);
    float4 s4 = *(const float4*)(sn + row * 128 + j0);
    f16x8 o;
    const float cc[4] = {c4.x, c4.y, c4.z, c4.w};
    const float ss[4] = {s4.x, s4.y, s4.z, s4.w};
#pragma unroll
    for (int p = 0; p < 4; ++p) {
      float x1 = (float)x[2 * p], x2 = (float)x[2 * p + 1];
      o[2 * p]     = (f16)(x1 * cc[p] - x2 * ss[p]);
      o[2 * p + 1] = (f16)(x2 * cc[p] + x1 * ss[p]);
    }
    *(f16x8*)base = o;
  }
}

// ---------------------------------------------------------------------------
// k_attn4: unified attention mega-kernel on gemm256 (256x256 tiles).
//   blocks [0, nop): oproj batch b_op (36 out0 + 8 out1 = 44)
//   blocks [nop, nop+npv): PV batch b_pv reading Psrc (8 heads x 6 = 48)
//   blocks [nop+npv, ...): scores batch b_sc (8 heads x 6x6 = 288)
// Long-K blocks dispatched first for tail packing.
// ---------------------------------------------------------------------------
__global__ __launch_bounds__(512, 2) void k_attn4(
    const f16* __restrict__ qb, const f16* __restrict__ kb,
    const f16* __restrict__ mask, f16* __restrict__ Sdst,
    const f16* __restrict__ Psrc, const f16* __restrict__ vt,
    f16* __restrict__ att0, f16* __restrict__ att1,
    const f16* __restrict__ wo0, const f16* __restrict__ wo1,
    float* __restrict__ out0, float* __restrict__ out1,
    int b_sc, int b_pv, int b_op, int npv, int nop)
{
  __shared__ alignas(16) f16 lds[65536];
  const int idx = blockIdx.x;
  if (idx < nop) {
    // output projection, K=2048
    int by, bx, ldc, rowb; const f16 *A, *B; float* C;
    if (idx < 36) { by = idx / 9; bx = idx % 9;
                    A = att0 + (size_t)(b_op * 4 + by) * 256 * 2048;
                    B = wo0 + (size_t)bx * 256 * 2048;
                    C = out0; ldc = 2304; rowb = b_op * 1024 + by * 256; }
    else          { int j = idx - 36; by = j >> 2; bx = j & 3;
                    A = att1 + (size_t)(b_op * 2 + by) * 256 * 2048;
                    B = wo1 + (size_t)bx * 256 * 2048;
                    C = out1; ldc = 1024; rowb = b_op * 512 + by * 256; }
    const int colb = bx * 256;
    gemm256(lds, A, 2048, B, 2048, 2048, [&](int r, int c, float fv) {
      C[(size_t)(rowb + r) * ldc + colb + c] = fv;
    });
  } else if (idx < nop + npv) {
    // PV, K=1536, N=256 (full head dim, P read once)
    const int j = idx - nop;
    const int h = j / 6, by = j % 6;
    const f16* A = Psrc + (size_t)h * 1536 * 1536 + (size_t)by * 256 * 1536;
    const f16* B = vt + (size_t)(b_pv * 4 + (h >> 1)) * 256 * 1536;
    f16* dst = (by < 4)
      ? att0 + (size_t)(b_pv * 1024 + by * 256) * 2048 + h * 256
      : att1 + (size_t)(b_pv * 512 + (by - 4) * 256) * 2048 + h * 256;
    gemm256(lds, A, 1536, B, 1536, 1536, [&](int r, int c, float fv) {
      dst[(size_t)r * 2048 + c] = (f16)fv;
    });
  } else {
    // scores, K=256
    const int j = idx - nop - npv;
    const int h = j / 36, rem = j % 36, by = rem / 6, bx = rem % 6;
    const f16* A = qb + (size_t)b_sc * 1536 * 2048 + h * 256 + (size_t)by * 256 * 2048;
    const f16* B = kb + (size_t)b_sc * 1536 * 1024 + (h >> 1) * 256 + (size_t)bx * 256 * 1024;
    f16* Sz = Sdst + (size_t)h * 1536 * 1536 + (size_t)by * 256 * 1536 + bx * 256;
    const f16* mb = mask + (size_t)b_sc * 1536 * 1536 + (size_t)by * 256 * 1536 + bx * 256;
    gemm256(lds, A, 2048, B, 1024, 256, [&](int r, int c, float fv) {
      size_t i = (size_t)r * 1536 + c;
      Sz[i] = (f16)(fv * 0.0625f + (float)mb[i]);
    });
  }
}

// ---- wave-per-row softmax over 1536, f16 in/out, in place ------------------
__global__ __launch_bounds__(256) void k_softmax(f16* __restrict__ S)
{
  const int row = blockIdx.x * 4 + (threadIdx.x >> 6);
  const int lane = threadIdx.x & 63;
  f16* p = S + (size_t)row * 1536 + lane * 8;
  f16x8 v0 = *(const f16x8*)p;
  f16x8 v1 = *(const f16x8*)(p + 512);
  f16x8 v2 = *(const f16x8*)(p + 1024);
  float x[24];
#pragma unroll
  for (int i = 0; i < 8; ++i) {
    x[i] = (float)v0[i]; x[8 + i] = (float)v1[i]; x[16 + i] = (float)v2[i];
  }
  float mx = x[0];
#pragma unroll
  for (int i = 1; i < 24; ++i) mx = fmaxf(mx, x[i]);
#pragma unroll
  for (int o = 32; o > 0; o >>= 1) mx = fmaxf(mx, __shfl_xor(mx, o, 64));
  float s = 0.f;
#pragma unroll
  for (int i = 0; i < 24; ++i) { x[i] = __expf(x[i] - mx); s += x[i]; }
#pragma unroll
  for (int o = 32; o > 0; o >>= 1) s += __shfl_xor(s, o, 64);
  const float inv = 1.f / s;
  f16x8 o0, o1, o2;
#pragma unroll
  for (int i = 0; i < 8; ++i) {
    o0[i] = (f16)(x[i] * inv); o1[i] = (f16)(x[8 + i] * inv); o2[i] = (f16)(x[16 + i] * inv);
  }
  *(f16x8*)p = o0; *(f16x8*)(p + 512) = o1; *(f16x8*)(p + 1024) = o2;
}

// ---- flat cast fp32->f16 (pg, ex, Wv0, Wo0, Wv1, Wo1) ----------------------
__global__ __launch_bounds__(256) void k_cast_all(
    const float* __restrict__ s0, const float* __restrict__ s1,
    const float* __restrict__ s2, const float* __restrict__ s3,
    const float* __restrict__ s4, const float* __restrict__ s5,
    f16* __restrict__ ws)
{
  const size_t gid = ((size_t)blockIdx.x * 256 + threadIdx.x) * 4;
  const float* s; size_t off, dst;
  if      (gid < 9437184ull)  { s = s0; off = gid;               dst = 0ull        + off; }
  else if (gid < 11534336ull) { s = s1; off = gid - 9437184ull;  dst = 9437184ull  + off; }
  else if (gid < 13893632ull) { s = s2; off = gid - 11534336ull; dst = 18612224ull + off; }
  else if (gid < 18612224ull) { s = s3; off = gid - 13893632ull; dst = 20971520ull + off; }
  else if (gid < 19660800ull) { s = s4; off = gid - 18612224ull; dst = 28835840ull + off; }
  else                        { s = s5; off = gid - 19660800ull; dst = 29884416ull + off; }
  float4 v = *(const float4*)(s + off);
  f16x4 o = {(f16)v.x, (f16)v.y, (f16)v.z, (f16)v.w};
  *(f16x4*)(ws + dst) = o;
}

// ---- Wq/Wk cast with per-head RoPE pair interleave: dst row h*256+w reads
// src row h*256 + (w>>1) + 128*(w&1).  One block per dst row. ---------------
__global__ __launch_bounds__(256) void k_cast_wr(
    const float* __restrict__ wq0, const float* __restrict__ wk0,
    const float* __restrict__ wq1, const float* __restrict__ wk1,
    f16* __restrict__ W0c, f16* __restrict__ W1c)
{
  const int idx = blockIdx.x;
  const float* src; f16* dstm; int K, r, drow;
  if      (idx < 2048) { src = wq0; dstm = W0c; K = 2304; r = idx;        drow = idx; }
  else if (idx < 3072) { src = wk0; dstm = W0c; K = 2304; r = idx - 2048; drow = idx; }
  else if (idx < 5120) { src = wq1; dstm = W1c; K = 1024; r = idx - 3072; drow = idx - 3072; }
  else                 { src = wk1; dstm = W1c; K = 1024; r = idx - 5120; drow = idx - 3072; }
  const int w = r & 255;
  const int srow = (r & ~255) + (w >> 1) + ((w & 1) << 7);
  const float* sp = src + (size_t)srow * K;
  f16* dp = dstm + (size_t)drow * K;
  for (int c = threadIdx.x * 4; c < K; c += 1024) {
    float4 v = *(const float4*)(sp + c);
    f16x4 o = {(f16)v.x, (f16)v.y, (f16)v.z, (f16)v.w};
    *(f16x4*)(dp + c) = o;
  }
}

// ---------------------------------------------------------------------------
extern "C" void kernel_launch(void* const* d_in, const int* in_sizes, int n_in,
                              void* d_out, int out_size, void* d_ws, size_t ws_size,
                              hipStream_t stream)
{
  (void)in_sizes; (void)n_in; (void)out_size; (void)ws_size;
  const float* pg  = (const float*)d_in[0];
  const float* ex  = (const float*)d_in[1];
  const float* cs  = (const float*)d_in[2];
  const float* sn  = (const float*)d_in[3];
  const float* msk = (const float*)d_in[4];

  char* ws = (char*)d_ws;
  f16* xpg  = (f16*)(ws + 0);           // [4096,2304]   (dead after qkv)
  f16* xex  = (f16*)(ws + 18874368);    // [2048,1024]   (dead after qkv)
  f16* W0c  = (f16*)(ws + 23068672);    // [4096,2304] Wq0i;Wk0i;Wv0 (dead after qkv)
  f16* wo0c = (f16*)(ws + 41943040);    // [2304,2048]
  f16* W1c  = (f16*)(ws + 51380224);    // [4096,1024] Wq1i;Wk1i;Wv1 (dead after qkv)
  f16* wo1c = (f16*)(ws + 59768832);    // [1024,2048]
  f16* qb   = (f16*)(ws + 63963136);    // [B*1536, 2048] f16, pair-interleaved
  f16* kb   = (f16*)(ws + 89128960);    // [B*1536, 1024]
  f16* vb   = (f16*)(ws + 101711872);   // [B*1536, 1024] (dead after post)
  f16* vt   = (f16*)(ws + 114294784);   // [B,4,256,1536]
  f16* att0 = (f16*)(ws + 126877696);   // [B*1024, 2048]
  f16* att1 = (f16*)(ws + 143654912);   // [B*512, 2048]
  f16* S0   = (f16*)(ws + 152043520);   // f16 S/P chunk A: 8*1536*1536
  f16* S1   = (f16*)(ws + 189792256);   // f16 S/P chunk B (ends 227,540,992)
  f16* mkh  = W0c;                      // f16 mask overlays dead W0c (18.9MB)
  float* out0 = (float*)d_out;          // [4,1024,2304]
  float* out1 = out0 + 9437184;         // [4,512,1024]

  // 1) casts
  k_cast_all<<<21248, 256, 0, stream>>>(
      pg, ex, (const float*)d_in[7], (const float*)d_in[8],
      (const float*)d_in[11], (const float*)d_in[12], (f16*)ws);
  k_cast_wr<<<6144, 256, 0, stream>>>(
      (const float*)d_in[5], (const float*)d_in[6],
      (const float*)d_in[9], (const float*)d_in[10], W0c, W1c);

  // 2) fused QKV (both streams) — 256x256-tile pipelined GEMM
  k_qkv5<<<384, 512, 0, stream>>>(xpg, xex, W0c, W1c, qb, kb, vb);

  // 3) merged post pass: vtrans + mask->f16 + in-place RoPE
  k_post<<<24576, 256, 0, stream>>>(qb, kb, cs, sn, msk, mkh, vb, vt);

  // 4) attention pipeline (double-buffered f16 S chunks); oproj(b) rides in
  //    the scores(b+2) launch.  Per batch: nop=44, npv=48, nsc=288.
  k_attn4<<<288, 512, 0, stream>>>(qb, kb, mkh, S0, S0, vt, att0, att1, wo0c, wo1c, out0, out1, 0, 0, 0, 0, 0);
  k_softmax<<<3072, 256, 0, stream>>>(S0);
  k_attn4<<<336, 512, 0, stream>>>(qb, kb, mkh, S1, S0, vt, att0, att1, wo0c, wo1c, out0, out1, 1, 0, 0, 48, 0);
  k_softmax<<<3072, 256, 0, stream>>>(S1);
  k_attn4<<<380, 512, 0, stream>>>(qb, kb, mkh, S0, S1, vt, att0, att1, wo0c, wo1c, out0, out1, 2, 1, 0, 48, 44);
  k_softmax<<<3072, 256, 0, stream>>>(S0);
  k_attn4<<<380, 512, 0, stream>>>(qb, kb, mkh, S1, S0, vt, att0, att1, wo0c, wo1c, out0, out1, 3, 2, 1, 48, 44);
  k_softmax<<<3072, 256, 0, stream>>>(S1);

  // 5) tail: PV b3 + oproj b2 (92), then oproj b3 (44)
  k_attn4<<<92, 512, 0, stream>>>(qb, kb, mkh, S0, S1, vt, att0, att1, wo0c, wo1c, out0, out1, 0, 3, 2, 48, 44);
  k_attn4<<<44, 512, 0, stream>>>(qb, kb, mkh, S0, S1, vt, att0, att1, wo0c, wo1c, out0, out1, 0, 0, 3, 0, 44);
}

// Round 5
// 642.809 us; speedup vs baseline: 1.1778x; 1.0613x over previous
//
#include <hip/hip_runtime.h>
#include <stdint.h>
#include <stddef.h>

// ---------------------------------------------------------------------------
// Gemma2AttentionWithExpert: fused two-stream QKV + RoPE + GQA attention +
// per-stream output projection.  All GEMMs via f16 MFMA (16x16x32), fp32 acc.
// B=4, L1=1024, L2=512, L=1536, D_PG=2304, D_EX=1024, H=8, HKV=4, DH=256.
// Round 9: recombination of best-measured parts:
//   - QKV: 256x256-tile gemm256 (R8 core; 104us, MfmaUtil 39.5%).
//   - Attention: R6's 256x128-tile gemm_pipe + launch schedule (576-760
//     blocks/launch -> good machine packing; R8's 256-wide tiles caused
//     tail quantization at 288-380 blocks and regressed 50us).
// ---------------------------------------------------------------------------

typedef _Float16 f16;
typedef _Float16 f16x8 __attribute__((ext_vector_type(8)));
typedef _Float16 f16x4 __attribute__((ext_vector_type(4)));
typedef float    f32x4 __attribute__((ext_vector_type(4)));

__device__ __forceinline__ void async_ld16(const void* g, void* l) {
  __builtin_amdgcn_global_load_lds((const __attribute__((address_space(1))) void*)g,
                                   (__attribute__((address_space(3))) void*)l,
                                   16, 0, 0);
}

// ---------------------------------------------------------------------------
// gemm256: 256x256 output tile, A:[256,lda] rm, B:[256,ldb] rm (B^T layout),
// K % 64 == 0.  512 threads = 8 waves (2M x 4N), wave tile 128x64.
// LDS 128KB double-buffered; per K-tile 2 phases of {vmcnt(4)|barrier|
// 12 ds_read_b128 | 4 global_load_lds | setprio(1) 32 MFMA setprio(0)|barrier}
// ---------------------------------------------------------------------------
template <typename Epi>
__device__ __forceinline__ void gemm256(f16* lds,
    const f16* __restrict__ A, int lda,
    const f16* __restrict__ B, int ldb,
    int K, Epi&& epi)
{
  const int t    = threadIdx.x;
  const int w    = t >> 6;
  const int lane = t & 63;
  const int q4   = lane >> 4;
  const int l16  = lane & 15;
  const int wm   = w >> 2;      // 0..1
  const int wn   = w & 3;       // 0..3

  f16* ldsA = lds;              // 2 buf x [2 ksub][256][32] f16 (64KB)
  f16* ldsB = lds + 32768;      // same (64KB)

  // staging: lane covers row (lane>>2) of a 16-row group, 16B chunk (lane&3)
  const f16* aP = A + (size_t)(lane >> 2) * lda + (lane & 3) * 8;
  const f16* bP = B + (size_t)(lane >> 2) * ldb + (lane & 3) * 8;
  const size_t aR0 = (size_t)(w * 32) * lda;        // wave's rowgroup 2w
  const size_t aR1 = aR0 + (size_t)16 * lda;        // rowgroup 2w+1
  const size_t bR0 = (size_t)(w * 32) * ldb;
  const size_t bR1 = bR0 + (size_t)16 * ldb;
  const int wo = w * 1024;      // dest f16 offset of wave's 2 rowgroups (2KB)

  // fragment read bases within a [256][32] ksub section (f16 units)
  const int arow = (wm * 128 + l16) * 32 + q4 * 8;
  const int brow = (wn * 64 + l16) * 32 + q4 * 8;

  f32x4 acc[8][4];
  const f32x4 vz = {0.f, 0.f, 0.f, 0.f};
#pragma unroll
  for (int i = 0; i < 8; ++i)
#pragma unroll
    for (int j = 0; j < 4; ++j) acc[i][j] = vz;

  // prologue: stage tile 0 (ksub0's 4 loads first, then ksub1's 4)
#pragma unroll
  for (int s = 0; s < 2; ++s) {
    const int kk = s * 32;
    async_ld16(aP + aR0 + kk, ldsA + s * 8192 + wo);
    async_ld16(aP + aR1 + kk, ldsA + s * 8192 + wo + 512);
    async_ld16(bP + bR0 + kk, ldsB + s * 8192 + wo);
    async_ld16(bP + bR1 + kk, ldsB + s * 8192 + wo + 512);
  }

  const int NT = K >> 6;
  for (int tk = 0; tk < NT; ++tk) {
    const int d  = (tk & 1) ? 16384 : 0;
    const int dn = 16384 - d;
    const bool st = tk + 1 < NT;
    const int kn = (tk + 1) << 6;
#pragma unroll
    for (int s = 0; s < 2; ++s) {
      // retire the 4 oldest loads (= ksub s of tile tk); keep 4 in flight
      if (s == 0 || st) asm volatile("s_waitcnt vmcnt(4)" ::: "memory");
      else              asm volatile("s_waitcnt vmcnt(0)" ::: "memory");
      asm volatile("s_barrier" ::: "memory");
      const f16* aS = ldsA + d + s * 8192;
      const f16* bS = ldsB + d + s * 8192;
      f16x8 af[8], bf[4];
#pragma unroll
      for (int i = 0; i < 8; ++i) af[i] = *(const f16x8*)(aS + arow + i * 512);
#pragma unroll
      for (int i = 0; i < 4; ++i) bf[i] = *(const f16x8*)(bS + brow + i * 512);
      if (st) {
        const int kk = kn + s * 32;
        async_ld16(aP + aR0 + kk, ldsA + dn + s * 8192 + wo);
        async_ld16(aP + aR1 + kk, ldsA + dn + s * 8192 + wo + 512);
        async_ld16(bP + bR0 + kk, ldsB + dn + s * 8192 + wo);
        async_ld16(bP + bR1 + kk, ldsB + dn + s * 8192 + wo + 512);
      }
      __builtin_amdgcn_s_setprio(1);
#pragma unroll
      for (int mi = 0; mi < 8; ++mi)
#pragma unroll
        for (int ni = 0; ni < 4; ++ni)
          acc[mi][ni] = __builtin_amdgcn_mfma_f32_16x16x32_f16(af[mi], bf[ni], acc[mi][ni], 0, 0, 0);
      __builtin_amdgcn_s_setprio(0);
      asm volatile("s_barrier" ::: "memory");
    }
  }

  // C/D layout (m89-verified): row = quad*4 + reg, col = lane&15
#pragma unroll
  for (int mi = 0; mi < 8; ++mi)
#pragma unroll
    for (int ni = 0; ni < 4; ++ni)
#pragma unroll
      for (int r = 0; r < 4; ++r)
        epi(wm * 128 + mi * 16 + q4 * 4 + r, wn * 64 + ni * 16 + l16, acc[mi][ni][r]);
}

// ---------------------------------------------------------------------------
// gemm_pipe: 256x128 output tile, A:[256,lda] rm, B:[128,ldb] rm (B^T layout),
// K%64==0, 512 threads = 8 waves (4M x 2N), wave tile 64x64.
// LDS 96KB: A 2buf x 2ksub x [256][32] + B 2buf x 2ksub x [128][32].
// Per K-tile: 2 phases {8 ds_read_b128 | 3 global_load_lds | vmcnt(3) |
// barrier | setprio(1) 16 MFMA setprio(0) | barrier}.
// ---------------------------------------------------------------------------
template <typename Epi>
__device__ __forceinline__ void gemm_pipe(f16* lds,
    const f16* __restrict__ A, int lda,
    const f16* __restrict__ B, int ldb,
    int K, Epi&& epi)
{
  const int t    = threadIdx.x;
  const int w    = t >> 6;
  const int lane = t & 63;
  const int q4   = lane >> 4;
  const int l16  = lane & 15;
  const int wm   = w >> 1;
  const int wn   = w & 1;

  // staging: wave w covers rows [w*16, w*16+16), 16B chunk (lane&3) of 64B row
  const int srow = w * 16 + (lane >> 2);
  const int scol = (lane & 3) * 8;
  const f16* aP = A + (size_t)srow * lda + scol;
  const f16* bP = B + (size_t)srow * ldb + scol;
  const size_t a128 = (size_t)128 * lda;
  const int wl = w * 512;             // per-wave 1KB LDS slice (f16 units)

  // fragment read bases within a [rows][32] ksub section (f16 units)
  const int arow = (wm * 64 + l16) * 32 + q4 * 8;
  const int brow = (wn * 64 + l16) * 32 + q4 * 8;

  f32x4 acc[4][4];
  const f32x4 vz = {0.f, 0.f, 0.f, 0.f};
#pragma unroll
  for (int i = 0; i < 4; ++i)
#pragma unroll
    for (int j = 0; j < 4; ++j) acc[i][j] = vz;

  // ---- prologue: stage tile 0 (k0 then k1); vmcnt(3) -> k0 landed ----------
  async_ld16(aP,             lds + wl);                 // A k0 rows 0-127
  async_ld16(aP + a128,      lds + 4096 + wl);          // A k0 rows 128-255
  async_ld16(bP,             lds + 32768 + wl);         // B k0
  asm volatile("" ::: "memory");
  async_ld16(aP + 32,        lds + 8192 + wl);          // A k1 rows 0-127
  async_ld16(aP + a128 + 32, lds + 8192 + 4096 + wl);   // A k1 rows 128-255
  async_ld16(bP + 32,        lds + 32768 + 4096 + wl);  // B k1
  asm volatile("s_waitcnt vmcnt(3)" ::: "memory");
  asm volatile("s_barrier" ::: "memory");

  const int NT = K >> 6;
  int cb = 0;
  for (int tk = 0; tk < NT; ++tk) {
    f16* aT = lds + cb * 16384;
    f16* bT = lds + 32768 + cb * 8192;
    f16* aD = lds + (cb ^ 1) * 16384;
    f16* bD = lds + 32768 + (cb ^ 1) * 8192;
    const int kn = (tk + 1) << 6;
    const bool st = tk < NT - 1;
#pragma unroll
    for (int s = 0; s < 2; ++s) {
      const f16* aS = aT + s * 8192;
      const f16* bS = bT + s * 4096;
      f16x8 af[4], bf[4];
#pragma unroll
      for (int i = 0; i < 4; ++i) {
        af[i] = *(const f16x8*)(aS + arow + i * 512);
        bf[i] = *(const f16x8*)(bS + brow + i * 512);
      }
      if (st) {
        if (s == 0) {
          async_ld16(aP + kn,        aD + wl);
          async_ld16(aP + a128 + kn, aD + 4096 + wl);
          async_ld16(bP + kn,        bD + wl);
        } else {
          async_ld16(aP + kn + 32,        aD + 8192 + wl);
          async_ld16(aP + a128 + kn + 32, aD + 8192 + 4096 + wl);
          async_ld16(bP + kn + 32,        bD + 4096 + wl);
        }
        asm volatile("s_waitcnt vmcnt(3)" ::: "memory");  // prev phase's 3 landed
      } else if (s == 0) {
        asm volatile("s_waitcnt vmcnt(0)" ::: "memory");  // last tile: k1 landed
      }
      asm volatile("s_barrier" ::: "memory");
      __builtin_amdgcn_s_setprio(1);
#pragma unroll
      for (int mi = 0; mi < 4; ++mi)
#pragma unroll
        for (int ni = 0; ni < 4; ++ni)
          acc[mi][ni] = __builtin_amdgcn_mfma_f32_16x16x32_f16(af[mi], bf[ni], acc[mi][ni], 0, 0, 0);
      __builtin_amdgcn_s_setprio(0);
      asm volatile("s_barrier" ::: "memory");
    }
    cb ^= 1;
  }

  // C/D layout (m89-verified): row = quad*4 + reg, col = lane&15
#pragma unroll
  for (int mi = 0; mi < 4; ++mi)
#pragma unroll
    for (int ni = 0; ni < 4; ++ni)
#pragma unroll
      for (int r = 0; r < 4; ++r)
        epi(wm * 64 + mi * 16 + q4 * 4 + r, wn * 64 + ni * 16 + l16, acc[mi][ni][r]);
}

// ---------------------------------------------------------------------------
// k_qkv5: fused QKV on gemm256.  blocks [0,256): stream0 (16x16 tiles,
// K=2304); [256,384): stream1 (8x16 tiles, K=1024).  N-tiles of 256:
// bx<8 q, 8-11 k, 12-15 v.
// ---------------------------------------------------------------------------
__global__ __launch_bounds__(512, 2) void k_qkv5(
    const f16* __restrict__ xpg, const f16* __restrict__ xex,
    const f16* __restrict__ W0,  const f16* __restrict__ W1,
    f16* __restrict__ q, f16* __restrict__ k, f16* __restrict__ v)
{
  __shared__ alignas(16) f16 lds[65536];
  const int idx = blockIdx.x;
  int by, bx, K; const f16 *A, *B;
  const bool s0 = idx < 256;
  if (s0) { by = idx >> 4; bx = idx & 15; K = 2304;
            A = xpg + (size_t)by * 256 * 2304; B = W0 + (size_t)bx * 256 * 2304; }
  else    { int j = idx - 256; by = j >> 4; bx = j & 15; K = 1024;
            A = xex + (size_t)by * 256 * 1024; B = W1 + (size_t)bx * 256 * 1024; }

  f16* D; int ldd, coff;
  if (bx < 8)       { D = q; ldd = 2048; coff = 0; }
  else if (bx < 12) { D = k; ldd = 1024; coff = 2048; }
  else              { D = v; ldd = 1024; coff = 3072; }
  const int colb = bx * 256 - coff;
  const int rowb = s0 ? ((by >> 2) * 1536 + (by & 3) * 256)
                      : ((by >> 1) * 1536 + 1024 + (by & 1) * 256);

  gemm256(lds, A, K, B, K, K, [&](int r, int c, float fv) {
    D[(size_t)(rowb + r) * ldd + colb + c] = (f16)fv;
  });
}

// ---- post pass: [0,6144) vtrans; [6144,15360) mask->f16; [15360,24576)
// in-place RoPE on pair-interleaved q/k (f16x8 = 4 pairs, float4 cos/sin) ----
__global__ __launch_bounds__(256) void k_post(
    f16* __restrict__ q, f16* __restrict__ k,
    const float* __restrict__ cs, const float* __restrict__ sn,
    const float* __restrict__ msk, f16* __restrict__ mkh,
    const f16* __restrict__ v, f16* __restrict__ vt)
{
  const int blk = blockIdx.x;
  if (blk < 6144) {
    // V transpose: v[B*1536,1024] -> vt[B][4][256][1536]
    __shared__ f16 tile[32][33];
    const int b = blk / 1536, r0 = blk % 1536;
    const int d0 = (r0 & 31) * 32, l0 = (r0 >> 5) * 32;
    const int t = threadIdx.x;
    const int tr = t >> 5, tc = t & 31;
#pragma unroll
    for (int i = 0; i < 4; ++i)
      tile[tr + i * 8][tc] = v[((size_t)b * 1536 + l0 + tr + i * 8) * 1024 + d0 + tc];
    __syncthreads();
#pragma unroll
    for (int i = 0; i < 4; ++i) {
      int d = d0 + tr + i * 8;
      vt[(((size_t)b * 4 + (d >> 8)) * 256 + (d & 255)) * 1536 + l0 + tc] = tile[tc][tr + i * 8];
    }
  } else if (blk < 15360) {
    const size_t gid = ((size_t)(blk - 6144) * 256 + threadIdx.x) * 4;
    float4 m4 = *(const float4*)(msk + gid);
    f16x4 o = {(f16)m4.x, (f16)m4.y, (f16)m4.z, (f16)m4.w};
    *(f16x4*)(mkh + gid) = o;
  } else {
    const size_t tid8 = ((size_t)(blk - 15360) * 256 + threadIdx.x) * 8;
    f16* base; size_t row; int col;
    if (tid8 < 12582912ull) { base = q + tid8; row = tid8 >> 11; col = (int)(tid8 & 2047); }
    else { size_t f = tid8 - 12582912ull; base = k + f; row = f >> 10; col = (int)(f & 1023); }
    const int j0 = (col & 255) >> 1;
    f16x8 x = *(const f16x8*)base;
    float4 c4 = *(const float4*)(cs + row * 128 + j0);
    float4 s4 = *(const float4*)(sn + row * 128 + j0);
    f16x8 o;
    const float cc[4] = {c4.x, c4.y, c4.z, c4.w};
    const float ss[4] = {s4.x, s4.y, s4.z, s4.w};
#pragma unroll
    for (int p = 0; p < 4; ++p) {
      float x1 = (float)x[2 * p], x2 = (float)x[2 * p + 1];
      o[2 * p]     = (f16)(x1 * cc[p] - x2 * ss[p]);
      o[2 * p + 1] = (f16)(x2 * cc[p] + x1 * ss[p]);
    }
    *(f16x8*)base = o;
  }
}

// ---------------------------------------------------------------------------
// k_attn2: unified attention mega-kernel on gemm_pipe (256x128 tiles).
//   blocks [0, nop): oproj batch b_op (72 out0 + 16 out1 = 88)
//   blocks [nop, nop+npv): PV batch b_pv reading Psrc (96)
//   blocks [nop+npv, ...): scores batch b_sc writing f16 Sdst (576)
// ---------------------------------------------------------------------------
__global__ __launch_bounds__(512, 2) void k_attn2(
    const f16* __restrict__ qb, const f16* __restrict__ kb,
    const f16* __restrict__ mask, f16* __restrict__ Sdst,
    const f16* __restrict__ Psrc, const f16* __restrict__ vt,
    f16* __restrict__ att0, f16* __restrict__ att1,
    const f16* __restrict__ wo0, const f16* __restrict__ wo1,
    float* __restrict__ out0, float* __restrict__ out1,
    int b_sc, int b_pv, int b_op, int npv, int nop)
{
  __shared__ alignas(16) f16 lds[49152];
  const int idx = blockIdx.x;
  if (idx < nop) {
    // output projection, K=2048
    int by, bx, ldc, rowb; const f16 *A, *B; float* C;
    if (idx < 72) { by = idx / 18; bx = idx % 18;
                    A = att0 + (size_t)(b_op * 4 + by) * 256 * 2048;
                    B = wo0 + (size_t)bx * 128 * 2048;
                    C = out0; ldc = 2304; rowb = b_op * 1024 + by * 256; }
    else          { int j = idx - 72; by = j >> 3; bx = j & 7;
                    A = att1 + (size_t)(b_op * 2 + by) * 256 * 2048;
                    B = wo1 + (size_t)bx * 128 * 2048;
                    C = out1; ldc = 1024; rowb = b_op * 512 + by * 256; }
    const int colb = bx * 128;
    gemm_pipe(lds, A, 2048, B, 2048, 2048, [&](int r, int c, float fv) {
      C[(size_t)(rowb + r) * ldc + colb + c] = fv;
    });
  } else if (idx < nop + npv) {
    // PV, K=1536
    const int j = idx - nop;
    const int h = j / 12, rem = j % 12, by = rem >> 1, bx = rem & 1;
    const f16* A = Psrc + (size_t)h * 1536 * 1536 + (size_t)by * 256 * 1536;
    const f16* B = vt + (size_t)(b_pv * 4 + (h >> 1)) * 256 * 1536 + (size_t)bx * 128 * 1536;
    f16* dst = (by < 4)
      ? att0 + (size_t)(b_pv * 1024 + by * 256) * 2048 + h * 256 + bx * 128
      : att1 + (size_t)(b_pv * 512 + (by - 4) * 256) * 2048 + h * 256 + bx * 128;
    gemm_pipe(lds, A, 1536, B, 1536, 1536, [&](int r, int c, float fv) {
      dst[(size_t)r * 2048 + c] = (f16)fv;
    });
  } else {
    // scores, K=256
    const int j = idx - nop - npv;
    const int h = j / 72, rem = j % 72, by = rem / 12, bx = rem % 12;
    const f16* A = qb + (size_t)b_sc * 1536 * 2048 + h * 256 + (size_t)by * 256 * 2048;
    const f16* B = kb + (size_t)b_sc * 1536 * 1024 + (h >> 1) * 256 + (size_t)bx * 128 * 1024;
    f16* Sz = Sdst + (size_t)h * 1536 * 1536 + (size_t)by * 256 * 1536 + bx * 128;
    const f16* mb = mask + (size_t)b_sc * 1536 * 1536 + (size_t)by * 256 * 1536 + bx * 128;
    gemm_pipe(lds, A, 2048, B, 1024, 256, [&](int r, int c, float fv) {
      size_t i = (size_t)r * 1536 + c;
      Sz[i] = (f16)(fv * 0.0625f + (float)mb[i]);
    });
  }
}

// ---- wave-per-row softmax over 1536, f16 in/out, in place ------------------
__global__ __launch_bounds__(256) void k_softmax(f16* __restrict__ S)
{
  const int row = blockIdx.x * 4 + (threadIdx.x >> 6);
  const int lane = threadIdx.x & 63;
  f16* p = S + (size_t)row * 1536 + lane * 8;
  f16x8 v0 = *(const f16x8*)p;
  f16x8 v1 = *(const f16x8*)(p + 512);
  f16x8 v2 = *(const f16x8*)(p + 1024);
  float x[24];
#pragma unroll
  for (int i = 0; i < 8; ++i) {
    x[i] = (float)v0[i]; x[8 + i] = (float)v1[i]; x[16 + i] = (float)v2[i];
  }
  float mx = x[0];
#pragma unroll
  for (int i = 1; i < 24; ++i) mx = fmaxf(mx, x[i]);
#pragma unroll
  for (int o = 32; o > 0; o >>= 1) mx = fmaxf(mx, __shfl_xor(mx, o, 64));
  float s = 0.f;
#pragma unroll
  for (int i = 0; i < 24; ++i) { x[i] = __expf(x[i] - mx); s += x[i]; }
#pragma unroll
  for (int o = 32; o > 0; o >>= 1) s += __shfl_xor(s, o, 64);
  const float inv = 1.f / s;
  f16x8 o0, o1, o2;
#pragma unroll
  for (int i = 0; i < 8; ++i) {
    o0[i] = (f16)(x[i] * inv); o1[i] = (f16)(x[8 + i] * inv); o2[i] = (f16)(x[16 + i] * inv);
  }
  *(f16x8*)p = o0; *(f16x8*)(p + 512) = o1; *(f16x8*)(p + 1024) = o2;
}

// ---- flat cast fp32->f16 (pg, ex, Wv0, Wo0, Wv1, Wo1) ----------------------
__global__ __launch_bounds__(256) void k_cast_all(
    const float* __restrict__ s0, const float* __restrict__ s1,
    const float* __restrict__ s2, const float* __restrict__ s3,
    const float* __restrict__ s4, const float* __restrict__ s5,
    f16* __restrict__ ws)
{
  const size_t gid = ((size_t)blockIdx.x * 256 + threadIdx.x) * 4;
  const float* s; size_t off, dst;
  if      (gid < 9437184ull)  { s = s0; off = gid;               dst = 0ull        + off; }
  else if (gid < 11534336ull) { s = s1; off = gid - 9437184ull;  dst = 9437184ull  + off; }
  else if (gid < 13893632ull) { s = s2; off = gid - 11534336ull; dst = 18612224ull + off; }
  else if (gid < 18612224ull) { s = s3; off = gid - 13893632ull; dst = 20971520ull + off; }
  else if (gid < 19660800ull) { s = s4; off = gid - 18612224ull; dst = 28835840ull + off; }
  else                        { s = s5; off = gid - 19660800ull; dst = 29884416ull + off; }
  float4 v = *(const float4*)(s + off);
  f16x4 o = {(f16)v.x, (f16)v.y, (f16)v.z, (f16)v.w};
  *(f16x4*)(ws + dst) = o;
}

// ---- Wq/Wk cast with per-head RoPE pair interleave: dst row h*256+w reads
// src row h*256 + (w>>1) + 128*(w&1).  One block per dst row. ---------------
__global__ __launch_bounds__(256) void k_cast_wr(
    const float* __restrict__ wq0, const float* __restrict__ wk0,
    const float* __restrict__ wq1, const float* __restrict__ wk1,
    f16* __restrict__ W0c, f16* __restrict__ W1c)
{
  const int idx = blockIdx.x;
  const float* src; f16* dstm; int K, r, drow;
  if      (idx < 2048) { src = wq0; dstm = W0c; K = 2304; r = idx;        drow = idx; }
  else if (idx < 3072) { src = wk0; dstm = W0c; K = 2304; r = idx - 2048; drow = idx; }
  else if (idx < 5120) { src = wq1; dstm = W1c; K = 1024; r = idx - 3072; drow = idx - 3072; }
  else                 { src = wk1; dstm = W1c; K = 1024; r = idx - 5120; drow = idx - 3072; }
  const int w = r & 255;
  const int srow = (r & ~255) + (w >> 1) + ((w & 1) << 7);
  const float* sp = src + (size_t)srow * K;
  f16* dp = dstm + (size_t)drow * K;
  for (int c = threadIdx.x * 4; c < K; c += 1024) {
    float4 v = *(const float4*)(sp + c);
    f16x4 o = {(f16)v.x, (f16)v.y, (f16)v.z, (f16)v.w};
    *(f16x4*)(dp + c) = o;
  }
}

// ---------------------------------------------------------------------------
extern "C" void kernel_launch(void* const* d_in, const int* in_sizes, int n_in,
                              void* d_out, int out_size, void* d_ws, size_t ws_size,
                              hipStream_t stream)
{
  (void)in_sizes; (void)n_in; (void)out_size; (void)ws_size;
  const float* pg  = (const float*)d_in[0];
  const float* ex  = (const float*)d_in[1];
  const float* cs  = (const float*)d_in[2];
  const float* sn  = (const float*)d_in[3];
  const float* msk = (const float*)d_in[4];

  char* ws = (char*)d_ws;
  f16* xpg  = (f16*)(ws + 0);           // [4096,2304]   (dead after qkv)
  f16* xex  = (f16*)(ws + 18874368);    // [2048,1024]   (dead after qkv)
  f16* W0c  = (f16*)(ws + 23068672);    // [4096,2304] Wq0i;Wk0i;Wv0 (dead after qkv)
  f16* wo0c = (f16*)(ws + 41943040);    // [2304,2048]
  f16* W1c  = (f16*)(ws + 51380224);    // [4096,1024] Wq1i;Wk1i;Wv1 (dead after qkv)
  f16* wo1c = (f16*)(ws + 59768832);    // [1024,2048]
  f16* qb   = (f16*)(ws + 63963136);    // [B*1536, 2048] f16, pair-interleaved
  f16* kb   = (f16*)(ws + 89128960);    // [B*1536, 1024]
  f16* vb   = (f16*)(ws + 101711872);   // [B*1536, 1024] (dead after post)
  f16* vt   = (f16*)(ws + 114294784);   // [B,4,256,1536]
  f16* att0 = (f16*)(ws + 126877696);   // [B*1024, 2048]
  f16* att1 = (f16*)(ws + 143654912);   // [B*512, 2048]
  f16* S0   = (f16*)(ws + 152043520);   // f16 S/P chunk A: 8*1536*1536
  f16* S1   = (f16*)(ws + 189792256);   // f16 S/P chunk B (ends 227,540,992)
  f16* mkh  = W0c;                      // f16 mask overlays dead W0c (18.9MB)
  float* out0 = (float*)d_out;          // [4,1024,2304]
  float* out1 = out0 + 9437184;         // [4,512,1024]

  // 1) casts
  k_cast_all<<<21248, 256, 0, stream>>>(
      pg, ex, (const float*)d_in[7], (const float*)d_in[8],
      (const float*)d_in[11], (const float*)d_in[12], (f16*)ws);
  k_cast_wr<<<6144, 256, 0, stream>>>(
      (const float*)d_in[5], (const float*)d_in[6],
      (const float*)d_in[9], (const float*)d_in[10], W0c, W1c);

  // 2) fused QKV (both streams) — 256x256-tile pipelined GEMM
  k_qkv5<<<384, 512, 0, stream>>>(xpg, xex, W0c, W1c, qb, kb, vb);

  // 3) merged post pass: vtrans + mask->f16 + in-place RoPE
  k_post<<<24576, 256, 0, stream>>>(qb, kb, cs, sn, msk, mkh, vb, vt);

  // 4) attention pipeline (double-buffered f16 S chunks); oproj(b) rides in
  //    the scores(b+2) launch.  Per batch: nop=88, npv=96, nsc=576.
  k_attn2<<<576, 512, 0, stream>>>(qb, kb, mkh, S0, S0, vt, att0, att1, wo0c, wo1c, out0, out1, 0, 0, 0, 0, 0);
  k_softmax<<<3072, 256, 0, stream>>>(S0);
  k_attn2<<<672, 512, 0, stream>>>(qb, kb, mkh, S1, S0, vt, att0, att1, wo0c, wo1c, out0, out1, 1, 0, 0, 96, 0);
  k_softmax<<<3072, 256, 0, stream>>>(S1);
  k_attn2<<<760, 512, 0, stream>>>(qb, kb, mkh, S0, S1, vt, att0, att1, wo0c, wo1c, out0, out1, 2, 1, 0, 96, 88);
  k_softmax<<<3072, 256, 0, stream>>>(S0);
  k_attn2<<<760, 512, 0, stream>>>(qb, kb, mkh, S1, S0, vt, att0, att1, wo0c, wo1c, out0, out1, 3, 2, 1, 96, 88);
  k_softmax<<<3072, 256, 0, stream>>>(S1);

  // 5) tail: PV b3 + oproj b2 (184), then oproj b3 (88)
  k_attn2<<<184, 512, 0, stream>>>(qb, kb, mkh, S0, S1, vt, att0, att1, wo0c, wo1c, out0, out1, 0, 3, 2, 96, 88);
  k_attn2<<<88, 512, 0, stream>>>(qb, kb, mkh, S0, S1, vt, att0, att1, wo0c, wo1c, out0, out1, 0, 0, 3, 0, 88);
}

// Round 6
// 632.414 us; speedup vs baseline: 1.1972x; 1.0164x over previous
//
#include <hip/hip_runtime.h>
#include <stdint.h>
#include <stddef.h>

// ---------------------------------------------------------------------------
// Gemma2AttentionWithExpert: fused two-stream QKV + RoPE + GQA attention +
// per-stream output projection.  All GEMMs via f16 MFMA (16x16x32), fp32 acc.
// B=4, L1=1024, L2=512, L=1536, D_PG=2304, D_EX=1024, H=8, HKV=4, DH=256.
// Round 10: LDS XOR-swizzle (T2) in BOTH GEMM cores.  [rows][32] f16 rows
// (64B) read as b128 by lane(q4,l16) had 8-way bank conflicts (8.65M cyc on
// qkv5).  Fix: slot' = q4 ^ ((row>>1)&3) on ds_read; global_load_lds dest
// stays linear so the GLOBAL source col chunk is pre-permuted by the same
// XOR ((lane&3) ^ ((lane>>3)&3)).  Rowgroup bases are multiples of 16 ->
// XOR term is lane-constant on both sides.  No sync-structure change.
// ---------------------------------------------------------------------------

typedef _Float16 f16;
typedef _Float16 f16x8 __attribute__((ext_vector_type(8)));
typedef _Float16 f16x4 __attribute__((ext_vector_type(4)));
typedef float    f32x4 __attribute__((ext_vector_type(4)));

__device__ __forceinline__ void async_ld16(const void* g, void* l) {
  __builtin_amdgcn_global_load_lds((const __attribute__((address_space(1))) void*)g,
                                   (__attribute__((address_space(3))) void*)l,
                                   16, 0, 0);
}

// ---------------------------------------------------------------------------
// gemm256: 256x256 output tile, A:[256,lda] rm, B:[256,ldb] rm (B^T layout),
// K % 64 == 0.  512 threads = 8 waves (2M x 4N), wave tile 128x64.
// LDS 128KB double-buffered; per K-tile 2 phases of {vmcnt(4)|barrier|
// 12 ds_read_b128 | 4 global_load_lds | setprio(1) 32 MFMA setprio(0)|barrier}
// LDS layout XOR-swizzled (see header comment).
// ---------------------------------------------------------------------------
template <typename Epi>
__device__ __forceinline__ void gemm256(f16* lds,
    const f16* __restrict__ A, int lda,
    const f16* __restrict__ B, int ldb,
    int K, Epi&& epi)
{
  const int t    = threadIdx.x;
  const int w    = t >> 6;
  const int lane = t & 63;
  const int q4   = lane >> 4;
  const int l16  = lane & 15;
  const int wm   = w >> 2;      // 0..1
  const int wn   = w & 3;       // 0..3

  f16* ldsA = lds;              // 2 buf x [2 ksub][256][32] f16 (64KB)
  f16* ldsB = lds + 32768;      // same (64KB)

  // staging: lane covers row (lane>>2) of a 16-row group; source 16B chunk is
  // XOR-permuted so the linear LDS dest realizes the swizzled layout.
  const int scx = ((lane & 3) ^ ((lane >> 3) & 3)) * 8;
  const f16* aP = A + (size_t)(lane >> 2) * lda + scx;
  const f16* bP = B + (size_t)(lane >> 2) * ldb + scx;
  const size_t aR0 = (size_t)(w * 32) * lda;        // wave's rowgroup 2w
  const size_t aR1 = aR0 + (size_t)16 * lda;        // rowgroup 2w+1
  const size_t bR0 = (size_t)(w * 32) * ldb;
  const size_t bR1 = bR0 + (size_t)16 * ldb;
  const int wo = w * 1024;      // dest f16 offset of wave's 2 rowgroups (2KB)

  // fragment read bases within a [256][32] ksub section (f16 units), swizzled
  const int sx = (l16 >> 1) & 3;
  const int arow = (wm * 128 + l16) * 32 + ((q4 ^ sx) * 8);
  const int brow = (wn * 64 + l16) * 32 + ((q4 ^ sx) * 8);

  f32x4 acc[8][4];
  const f32x4 vz = {0.f, 0.f, 0.f, 0.f};
#pragma unroll
  for (int i = 0; i < 8; ++i)
#pragma unroll
    for (int j = 0; j < 4; ++j) acc[i][j] = vz;

  // prologue: stage tile 0 (ksub0's 4 loads first, then ksub1's 4)
#pragma unroll
  for (int s = 0; s < 2; ++s) {
    const int kk = s * 32;
    async_ld16(aP + aR0 + kk, ldsA + s * 8192 + wo);
    async_ld16(aP + aR1 + kk, ldsA + s * 8192 + wo + 512);
    async_ld16(bP + bR0 + kk, ldsB + s * 8192 + wo);
    async_ld16(bP + bR1 + kk, ldsB + s * 8192 + wo + 512);
  }

  const int NT = K >> 6;
  for (int tk = 0; tk < NT; ++tk) {
    const int d  = (tk & 1) ? 16384 : 0;
    const int dn = 16384 - d;
    const bool st = tk + 1 < NT;
    const int kn = (tk + 1) << 6;
#pragma unroll
    for (int s = 0; s < 2; ++s) {
      // retire the 4 oldest loads (= ksub s of tile tk); keep 4 in flight
      if (s == 0 || st) asm volatile("s_waitcnt vmcnt(4)" ::: "memory");
      else              asm volatile("s_waitcnt vmcnt(0)" ::: "memory");
      asm volatile("s_barrier" ::: "memory");
      const f16* aS = ldsA + d + s * 8192;
      const f16* bS = ldsB + d + s * 8192;
      f16x8 af[8], bf[4];
#pragma unroll
      for (int i = 0; i < 8; ++i) af[i] = *(const f16x8*)(aS + arow + i * 512);
#pragma unroll
      for (int i = 0; i < 4; ++i) bf[i] = *(const f16x8*)(bS + brow + i * 512);
      if (st) {
        const int kk = kn + s * 32;
        async_ld16(aP + aR0 + kk, ldsA + dn + s * 8192 + wo);
        async_ld16(aP + aR1 + kk, ldsA + dn + s * 8192 + wo + 512);
        async_ld16(bP + bR0 + kk, ldsB + dn + s * 8192 + wo);
        async_ld16(bP + bR1 + kk, ldsB + dn + s * 8192 + wo + 512);
      }
      __builtin_amdgcn_s_setprio(1);
#pragma unroll
      for (int mi = 0; mi < 8; ++mi)
#pragma unroll
        for (int ni = 0; ni < 4; ++ni)
          acc[mi][ni] = __builtin_amdgcn_mfma_f32_16x16x32_f16(af[mi], bf[ni], acc[mi][ni], 0, 0, 0);
      __builtin_amdgcn_s_setprio(0);
      asm volatile("s_barrier" ::: "memory");
    }
  }

  // C/D layout (m89-verified): row = quad*4 + reg, col = lane&15
#pragma unroll
  for (int mi = 0; mi < 8; ++mi)
#pragma unroll
    for (int ni = 0; ni < 4; ++ni)
#pragma unroll
      for (int r = 0; r < 4; ++r)
        epi(wm * 128 + mi * 16 + q4 * 4 + r, wn * 64 + ni * 16 + l16, acc[mi][ni][r]);
}

// ---------------------------------------------------------------------------
// gemm_pipe: 256x128 output tile, A:[256,lda] rm, B:[128,ldb] rm (B^T layout),
// K%64==0, 512 threads = 8 waves (4M x 2N), wave tile 64x64.
// LDS 96KB: A 2buf x 2ksub x [256][32] + B 2buf x 2ksub x [128][32].
// Per K-tile: 2 phases {8 ds_read_b128 | 3 global_load_lds | vmcnt(3) |
// barrier | setprio(1) 16 MFMA setprio(0) | barrier}.  Same XOR swizzle.
// ---------------------------------------------------------------------------
template <typename Epi>
__device__ __forceinline__ void gemm_pipe(f16* lds,
    const f16* __restrict__ A, int lda,
    const f16* __restrict__ B, int ldb,
    int K, Epi&& epi)
{
  const int t    = threadIdx.x;
  const int w    = t >> 6;
  const int lane = t & 63;
  const int q4   = lane >> 4;
  const int l16  = lane & 15;
  const int wm   = w >> 1;
  const int wn   = w & 1;

  // staging: wave w covers rows [w*16, w*16+16); source 16B chunk XOR-permuted
  const int srow = w * 16 + (lane >> 2);
  const int scol = ((lane & 3) ^ ((lane >> 3) & 3)) * 8;
  const f16* aP = A + (size_t)srow * lda + scol;
  const f16* bP = B + (size_t)srow * ldb + scol;
  const size_t a128 = (size_t)128 * lda;
  const int wl = w * 512;             // per-wave 1KB LDS slice (f16 units)

  // fragment read bases within a [rows][32] ksub section (f16 units), swizzled
  const int sx = (l16 >> 1) & 3;
  const int arow = (wm * 64 + l16) * 32 + ((q4 ^ sx) * 8);
  const int brow = (wn * 64 + l16) * 32 + ((q4 ^ sx) * 8);

  f32x4 acc[4][4];
  const f32x4 vz = {0.f, 0.f, 0.f, 0.f};
#pragma unroll
  for (int i = 0; i < 4; ++i)
#pragma unroll
    for (int j = 0; j < 4; ++j) acc[i][j] = vz;

  // ---- prologue: stage tile 0 (k0 then k1); vmcnt(3) -> k0 landed ----------
  async_ld16(aP,             lds + wl);                 // A k0 rows 0-127
  async_ld16(aP + a128,      lds + 4096 + wl);          // A k0 rows 128-255
  async_ld16(bP,             lds + 32768 + wl);         // B k0
  asm volatile("" ::: "memory");
  async_ld16(aP + 32,        lds + 8192 + wl);          // A k1 rows 0-127
  async_ld16(aP + a128 + 32, lds + 8192 + 4096 + wl);   // A k1 rows 128-255
  async_ld16(bP + 32,        lds + 32768 + 4096 + wl);  // B k1
  asm volatile("s_waitcnt vmcnt(3)" ::: "memory");
  asm volatile("s_barrier" ::: "memory");

  const int NT = K >> 6;
  int cb = 0;
  for (int tk = 0; tk < NT; ++tk) {
    f16* aT = lds + cb * 16384;
    f16* bT = lds + 32768 + cb * 8192;
    f16* aD = lds + (cb ^ 1) * 16384;
    f16* bD = lds + 32768 + (cb ^ 1) * 8192;
    const int kn = (tk + 1) << 6;
    const bool st = tk < NT - 1;
#pragma unroll
    for (int s = 0; s < 2; ++s) {
      const f16* aS = aT + s * 8192;
      const f16* bS = bT + s * 4096;
      f16x8 af[4], bf[4];
#pragma unroll
      for (int i = 0; i < 4; ++i) {
        af[i] = *(const f16x8*)(aS + arow + i * 512);
        bf[i] = *(const f16x8*)(bS + brow + i * 512);
      }
      if (st) {
        if (s == 0) {
          async_ld16(aP + kn,        aD + wl);
          async_ld16(aP + a128 + kn, aD + 4096 + wl);
          async_ld16(bP + kn,        bD + wl);
        } else {
          async_ld16(aP + kn + 32,        aD + 8192 + wl);
          async_ld16(aP + a128 + kn + 32, aD + 8192 + 4096 + wl);
          async_ld16(bP + kn + 32,        bD + 4096 + wl);
        }
        asm volatile("s_waitcnt vmcnt(3)" ::: "memory");  // prev phase's 3 landed
      } else if (s == 0) {
        asm volatile("s_waitcnt vmcnt(0)" ::: "memory");  // last tile: k1 landed
      }
      asm volatile("s_barrier" ::: "memory");
      __builtin_amdgcn_s_setprio(1);
#pragma unroll
      for (int mi = 0; mi < 4; ++mi)
#pragma unroll
        for (int ni = 0; ni < 4; ++ni)
          acc[mi][ni] = __builtin_amdgcn_mfma_f32_16x16x32_f16(af[mi], bf[ni], acc[mi][ni], 0, 0, 0);
      __builtin_amdgcn_s_setprio(0);
      asm volatile("s_barrier" ::: "memory");
    }
    cb ^= 1;
  }

  // C/D layout (m89-verified): row = quad*4 + reg, col = lane&15
#pragma unroll
  for (int mi = 0; mi < 4; ++mi)
#pragma unroll
    for (int ni = 0; ni < 4; ++ni)
#pragma unroll
      for (int r = 0; r < 4; ++r)
        epi(wm * 64 + mi * 16 + q4 * 4 + r, wn * 64 + ni * 16 + l16, acc[mi][ni][r]);
}

// ---------------------------------------------------------------------------
// k_qkv5: fused QKV on gemm256.  blocks [0,256): stream0 (16x16 tiles,
// K=2304); [256,384): stream1 (8x16 tiles, K=1024).  N-tiles of 256:
// bx<8 q, 8-11 k, 12-15 v.
// ---------------------------------------------------------------------------
__global__ __launch_bounds__(512, 2) void k_qkv5(
    const f16* __restrict__ xpg, const f16* __restrict__ xex,
    const f16* __restrict__ W0,  const f16* __restrict__ W1,
    f16* __restrict__ q, f16* __restrict__ k, f16* __restrict__ v)
{
  __shared__ alignas(16) f16 lds[65536];
  const int idx = blockIdx.x;
  int by, bx, K; const f16 *A, *B;
  const bool s0 = idx < 256;
  if (s0) { by = idx >> 4; bx = idx & 15; K = 2304;
            A = xpg + (size_t)by * 256 * 2304; B = W0 + (size_t)bx * 256 * 2304; }
  else    { int j = idx - 256; by = j >> 4; bx = j & 15; K = 1024;
            A = xex + (size_t)by * 256 * 1024; B = W1 + (size_t)bx * 256 * 1024; }

  f16* D; int ldd, coff;
  if (bx < 8)       { D = q; ldd = 2048; coff = 0; }
  else if (bx < 12) { D = k; ldd = 1024; coff = 2048; }
  else              { D = v; ldd = 1024; coff = 3072; }
  const int colb = bx * 256 - coff;
  const int rowb = s0 ? ((by >> 2) * 1536 + (by & 3) * 256)
                      : ((by >> 1) * 1536 + 1024 + (by & 1) * 256);

  gemm256(lds, A, K, B, K, K, [&](int r, int c, float fv) {
    D[(size_t)(rowb + r) * ldd + colb + c] = (f16)fv;
  });
}

// ---- post pass: [0,6144) vtrans; [6144,15360) mask->f16; [15360,24576)
// in-place RoPE on pair-interleaved q/k (f16x8 = 4 pairs, float4 cos/sin) ----
__global__ __launch_bounds__(256) void k_post(
    f16* __restrict__ q, f16* __restrict__ k,
    const float* __restrict__ cs, const float* __restrict__ sn,
    const float* __restrict__ msk, f16* __restrict__ mkh,
    const f16* __restrict__ v, f16* __restrict__ vt)
{
  const int blk = blockIdx.x;
  if (blk < 6144) {
    // V transpose: v[B*1536,1024] -> vt[B][4][256][1536]
    __shared__ f16 tile[32][33];
    const int b = blk / 1536, r0 = blk % 1536;
    const int d0 = (r0 & 31) * 32, l0 = (r0 >> 5) * 32;
    const int t = threadIdx.x;
    const int tr = t >> 5, tc = t & 31;
#pragma unroll
    for (int i = 0; i < 4; ++i)
      tile[tr + i * 8][tc] = v[((size_t)b * 1536 + l0 + tr + i * 8) * 1024 + d0 + tc];
    __syncthreads();
#pragma unroll
    for (int i = 0; i < 4; ++i) {
      int d = d0 + tr + i * 8;
      vt[(((size_t)b * 4 + (d >> 8)) * 256 + (d & 255)) * 1536 + l0 + tc] = tile[tc][tr + i * 8];
    }
  } else if (blk < 15360) {
    const size_t gid = ((size_t)(blk - 6144) * 256 + threadIdx.x) * 4;
    float4 m4 = *(const float4*)(msk + gid);
    f16x4 o = {(f16)m4.x, (f16)m4.y, (f16)m4.z, (f16)m4.w};
    *(f16x4*)(mkh + gid) = o;
  } else {
    const size_t tid8 = ((size_t)(blk - 15360) * 256 + threadIdx.x) * 8;
    f16* base; size_t row; int col;
    if (tid8 < 12582912ull) { base = q + tid8; row = tid8 >> 11; col = (int)(tid8 & 2047); }
    else { size_t f = tid8 - 12582912ull; base = k + f; row = f >> 10; col = (int)(f & 1023); }
    const int j0 = (col & 255) >> 1;
    f16x8 x = *(const f16x8*)base;
    float4 c4 = *(const float4*)(cs + row * 128 + j0);
    float4 s4 = *(const float4*)(sn + row * 128 + j0);
    f16x8 o;
    const float cc[4] = {c4.x, c4.y, c4.z, c4.w};
    const float ss[4] = {s4.x, s4.y, s4.z, s4.w};
#pragma unroll
    for (int p = 0; p < 4; ++p) {
      float x1 = (float)x[2 * p], x2 = (float)x[2 * p + 1];
      o[2 * p]     = (f16)(x1 * cc[p] - x2 * ss[p]);
      o[2 * p + 1] = (f16)(x2 * cc[p] + x1 * ss[p]);
    }
    *(f16x8*)base = o;
  }
}

// ---------------------------------------------------------------------------
// k_attn2: unified attention mega-kernel on gemm_pipe (256x128 tiles).
//   blocks [0, nop): oproj batch b_op (72 out0 + 16 out1 = 88)
//   blocks [nop, nop+npv): PV batch b_pv reading Psrc (96)
//   blocks [nop+npv, ...): scores batch b_sc writing f16 Sdst (576)
// ---------------------------------------------------------------------------
__global__ __launch_bounds__(512, 2) void k_attn2(
    const f16* __restrict__ qb, const f16* __restrict__ kb,
    const f16* __restrict__ mask, f16* __restrict__ Sdst,
    const f16* __restrict__ Psrc, const f16* __restrict__ vt,
    f16* __restrict__ att0, f16* __restrict__ att1,
    const f16* __restrict__ wo0, const f16* __restrict__ wo1,
    float* __restrict__ out0, float* __restrict__ out1,
    int b_sc, int b_pv, int b_op, int npv, int nop)
{
  __shared__ alignas(16) f16 lds[49152];
  const int idx = blockIdx.x;
  if (idx < nop) {
    // output projection, K=2048
    int by, bx, ldc, rowb; const f16 *A, *B; float* C;
    if (idx < 72) { by = idx / 18; bx = idx % 18;
                    A = att0 + (size_t)(b_op * 4 + by) * 256 * 2048;
                    B = wo0 + (size_t)bx * 128 * 2048;
                    C = out0; ldc = 2304; rowb = b_op * 1024 + by * 256; }
    else          { int j = idx - 72; by = j >> 3; bx = j & 7;
                    A = att1 + (size_t)(b_op * 2 + by) * 256 * 2048;
                    B = wo1 + (size_t)bx * 128 * 2048;
                    C = out1; ldc = 1024; rowb = b_op * 512 + by * 256; }
    const int colb = bx * 128;
    gemm_pipe(lds, A, 2048, B, 2048, 2048, [&](int r, int c, float fv) {
      C[(size_t)(rowb + r) * ldc + colb + c] = fv;
    });
  } else if (idx < nop + npv) {
    // PV, K=1536
    const int j = idx - nop;
    const int h = j / 12, rem = j % 12, by = rem >> 1, bx = rem & 1;
    const f16* A = Psrc + (size_t)h * 1536 * 1536 + (size_t)by * 256 * 1536;
    const f16* B = vt + (size_t)(b_pv * 4 + (h >> 1)) * 256 * 1536 + (size_t)bx * 128 * 1536;
    f16* dst = (by < 4)
      ? att0 + (size_t)(b_pv * 1024 + by * 256) * 2048 + h * 256 + bx * 128
      : att1 + (size_t)(b_pv * 512 + (by - 4) * 256) * 2048 + h * 256 + bx * 128;
    gemm_pipe(lds, A, 1536, B, 1536, 1536, [&](int r, int c, float fv) {
      dst[(size_t)r * 2048 + c] = (f16)fv;
    });
  } else {
    // scores, K=256
    const int j = idx - nop - npv;
    const int h = j / 72, rem = j % 72, by = rem / 12, bx = rem % 12;
    const f16* A = qb + (size_t)b_sc * 1536 * 2048 + h * 256 + (size_t)by * 256 * 2048;
    const f16* B = kb + (size_t)b_sc * 1536 * 1024 + (h >> 1) * 256 + (size_t)bx * 128 * 1024;
    f16* Sz = Sdst + (size_t)h * 1536 * 1536 + (size_t)by * 256 * 1536 + bx * 128;
    const f16* mb = mask + (size_t)b_sc * 1536 * 1536 + (size_t)by * 256 * 1536 + bx * 128;
    gemm_pipe(lds, A, 2048, B, 1024, 256, [&](int r, int c, float fv) {
      size_t i = (size_t)r * 1536 + c;
      Sz[i] = (f16)(fv * 0.0625f + (float)mb[i]);
    });
  }
}

// ---- wave-per-row softmax over 1536, f16 in/out, in place ------------------
__global__ __launch_bounds__(256) void k_softmax(f16* __restrict__ S)
{
  const int row = blockIdx.x * 4 + (threadIdx.x >> 6);
  const int lane = threadIdx.x & 63;
  f16* p = S + (size_t)row * 1536 + lane * 8;
  f16x8 v0 = *(const f16x8*)p;
  f16x8 v1 = *(const f16x8*)(p + 512);
  f16x8 v2 = *(const f16x8*)(p + 1024);
  float x[24];
#pragma unroll
  for (int i = 0; i < 8; ++i) {
    x[i] = (float)v0[i]; x[8 + i] = (float)v1[i]; x[16 + i] = (float)v2[i];
  }
  float mx = x[0];
#pragma unroll
  for (int i = 1; i < 24; ++i) mx = fmaxf(mx, x[i]);
#pragma unroll
  for (int o = 32; o > 0; o >>= 1) mx = fmaxf(mx, __shfl_xor(mx, o, 64));
  float s = 0.f;
#pragma unroll
  for (int i = 0; i < 24; ++i) { x[i] = __expf(x[i] - mx); s += x[i]; }
#pragma unroll
  for (int o = 32; o > 0; o >>= 1) s += __shfl_xor(s, o, 64);
  const float inv = 1.f / s;
  f16x8 o0, o1, o2;
#pragma unroll
  for (int i = 0; i < 8; ++i) {
    o0[i] = (f16)(x[i] * inv); o1[i] = (f16)(x[8 + i] * inv); o2[i] = (f16)(x[16 + i] * inv);
  }
  *(f16x8*)p = o0; *(f16x8*)(p + 512) = o1; *(f16x8*)(p + 1024) = o2;
}

// ---- flat cast fp32->f16 (pg, ex, Wv0, Wo0, Wv1, Wo1) ----------------------
__global__ __launch_bounds__(256) void k_cast_all(
    const float* __restrict__ s0, const float* __restrict__ s1,
    const float* __restrict__ s2, const float* __restrict__ s3,
    const float* __restrict__ s4, const float* __restrict__ s5,
    f16* __restrict__ ws)
{
  const size_t gid = ((size_t)blockIdx.x * 256 + threadIdx.x) * 4;
  const float* s; size_t off, dst;
  if      (gid < 9437184ull)  { s = s0; off = gid;               dst = 0ull        + off; }
  else if (gid < 11534336ull) { s = s1; off = gid - 9437184ull;  dst = 9437184ull  + off; }
  else if (gid < 13893632ull) { s = s2; off = gid - 11534336ull; dst = 18612224ull + off; }
  else if (gid < 18612224ull) { s = s3; off = gid - 13893632ull; dst = 20971520ull + off; }
  else if (gid < 19660800ull) { s = s4; off = gid - 18612224ull; dst = 28835840ull + off; }
  else                        { s = s5; off = gid - 19660800ull; dst = 29884416ull + off; }
  float4 v = *(const float4*)(s + off);
  f16x4 o = {(f16)v.x, (f16)v.y, (f16)v.z, (f16)v.w};
  *(f16x4*)(ws + dst) = o;
}

// ---- Wq/Wk cast with per-head RoPE pair interleave: dst row h*256+w reads
// src row h*256 + (w>>1) + 128*(w&1).  One block per dst row. ---------------
__global__ __launch_bounds__(256) void k_cast_wr(
    const float* __restrict__ wq0, const float* __restrict__ wk0,
    const float* __restrict__ wq1, const float* __restrict__ wk1,
    f16* __restrict__ W0c, f16* __restrict__ W1c)
{
  const int idx = blockIdx.x;
  const float* src; f16* dstm; int K, r, drow;
  if      (idx < 2048) { src = wq0; dstm = W0c; K = 2304; r = idx;        drow = idx; }
  else if (idx < 3072) { src = wk0; dstm = W0c; K = 2304; r = idx - 2048; drow = idx; }
  else if (idx < 5120) { src = wq1; dstm = W1c; K = 1024; r = idx - 3072; drow = idx - 3072; }
  else                 { src = wk1; dstm = W1c; K = 1024; r = idx - 5120; drow = idx - 3072; }
  const int w = r & 255;
  const int srow = (r & ~255) + (w >> 1) + ((w & 1) << 7);
  const float* sp = src + (size_t)srow * K;
  f16* dp = dstm + (size_t)drow * K;
  for (int c = threadIdx.x * 4; c < K; c += 1024) {
    float4 v = *(const float4*)(sp + c);
    f16x4 o = {(f16)v.x, (f16)v.y, (f16)v.z, (f16)v.w};
    *(f16x4*)(dp + c) = o;
  }
}

// ---------------------------------------------------------------------------
extern "C" void kernel_launch(void* const* d_in, const int* in_sizes, int n_in,
                              void* d_out, int out_size, void* d_ws, size_t ws_size,
                              hipStream_t stream)
{
  (void)in_sizes; (void)n_in; (void)out_size; (void)ws_size;
  const float* pg  = (const float*)d_in[0];
  const float* ex  = (const float*)d_in[1];
  const float* cs  = (const float*)d_in[2];
  const float* sn  = (const float*)d_in[3];
  const float* msk = (const float*)d_in[4];

  char* ws = (char*)d_ws;
  f16* xpg  = (f16*)(ws + 0);           // [4096,2304]   (dead after qkv)
  f16* xex  = (f16*)(ws + 18874368);    // [2048,1024]   (dead after qkv)
  f16* W0c  = (f16*)(ws + 23068672);    // [4096,2304] Wq0i;Wk0i;Wv0 (dead after qkv)
  f16* wo0c = (f16*)(ws + 41943040);    // [2304,2048]
  f16* W1c  = (f16*)(ws + 51380224);    // [4096,1024] Wq1i;Wk1i;Wv1 (dead after qkv)
  f16* wo1c = (f16*)(ws + 59768832);    // [1024,2048]
  f16* qb   = (f16*)(ws + 63963136);    // [B*1536, 2048] f16, pair-interleaved
  f16* kb   = (f16*)(ws + 89128960);    // [B*1536, 1024]
  f16* vb   = (f16*)(ws + 101711872);   // [B*1536, 1024] (dead after post)
  f16* vt   = (f16*)(ws + 114294784);   // [B,4,256,1536]
  f16* att0 = (f16*)(ws + 126877696);   // [B*1024, 2048]
  f16* att1 = (f16*)(ws + 143654912);   // [B*512, 2048]
  f16* S0   = (f16*)(ws + 152043520);   // f16 S/P chunk A: 8*1536*1536
  f16* S1   = (f16*)(ws + 189792256);   // f16 S/P chunk B (ends 227,540,992)
  f16* mkh  = W0c;                      // f16 mask overlays dead W0c (18.9MB)
  float* out0 = (float*)d_out;          // [4,1024,2304]
  float* out1 = out0 + 9437184;         // [4,512,1024]

  // 1) casts
  k_cast_all<<<21248, 256, 0, stream>>>(
      pg, ex, (const float*)d_in[7], (const float*)d_in[8],
      (const float*)d_in[11], (const float*)d_in[12], (f16*)ws);
  k_cast_wr<<<6144, 256, 0, stream>>>(
      (const float*)d_in[5], (const float*)d_in[6],
      (const float*)d_in[9], (const float*)d_in[10], W0c, W1c);

  // 2) fused QKV (both streams) — 256x256-tile pipelined GEMM
  k_qkv5<<<384, 512, 0, stream>>>(xpg, xex, W0c, W1c, qb, kb, vb);

  // 3) merged post pass: vtrans + mask->f16 + in-place RoPE
  k_post<<<24576, 256, 0, stream>>>(qb, kb, cs, sn, msk, mkh, vb, vt);

  // 4) attention pipeline (double-buffered f16 S chunks); oproj(b) rides in
  //    the scores(b+2) launch.  Per batch: nop=88, npv=96, nsc=576.
  k_attn2<<<576, 512, 0, stream>>>(qb, kb, mkh, S0, S0, vt, att0, att1, wo0c, wo1c, out0, out1, 0, 0, 0, 0, 0);
  k_softmax<<<3072, 256, 0, stream>>>(S0);
  k_attn2<<<672, 512, 0, stream>>>(qb, kb, mkh, S1, S0, vt, att0, att1, wo0c, wo1c, out0, out1, 1, 0, 0, 96, 0);
  k_softmax<<<3072, 256, 0, stream>>>(S1);
  k_attn2<<<760, 512, 0, stream>>>(qb, kb, mkh, S0, S1, vt, att0, att1, wo0c, wo1c, out0, out1, 2, 1, 0, 96, 88);
  k_softmax<<<3072, 256, 0, stream>>>(S0);
  k_attn2<<<760, 512, 0, stream>>>(qb, kb, mkh, S1, S0, vt, att0, att1, wo0c, wo1c, out0, out1, 3, 2, 1, 96, 88);
  k_softmax<<<3072, 256, 0, stream>>>(S1);

  // 5) tail: PV b3 + oproj b2 (184), then oproj b3 (88)
  k_attn2<<<184, 512, 0, stream>>>(qb, kb, mkh, S0, S1, vt, att0, att1, wo0c, wo1c, out0, out1, 0, 3, 2, 96, 88);
  k_attn2<<<88, 512, 0, stream>>>(qb, kb, mkh, S0, S1, vt, att0, att1, wo0c, wo1c, out0, out1, 0, 0, 3, 0, 88);
}

// Round 7
// 630.717 us; speedup vs baseline: 1.2004x; 1.0027x over previous
//
#include <hip/hip_runtime.h>
#include <stdint.h>
#include <stddef.h>

// ---------------------------------------------------------------------------
// Gemma2AttentionWithExpert: fused two-stream QKV + RoPE + GQA attention +
// per-stream output projection.  All GEMMs via f16 MFMA (16x16x32), fp32 acc.
// B=4, L1=1024, L2=512, L=1536, D_PG=2304, D_EX=1024, H=8, HKV=4, DH=256.
// Round 11: gemm256 restructured to the m201 4-fine-phase schedule:
//   per K-tile: 4 phases x {ds_read subtile || 2 global_load_lds -> barrier
//   -> setprio(1) 16 MFMA setprio(0) -> barrier}; counted vmcnt(4) only at
//   phases 2 & 4 (retire prev ksub / next tile's ksub0), never 0 mid-loop.
//   Reads issue BEFORE the barrier (latency hides under arrival skew) --
//   this was already gemm_pipe's shape and is why R10's conflict-fix didn't
//   pay on gemm256's read-after-barrier order.  LDS swizzle (R10) retained.
// ---------------------------------------------------------------------------

typedef _Float16 f16;
typedef _Float16 f16x8 __attribute__((ext_vector_type(8)));
typedef _Float16 f16x4 __attribute__((ext_vector_type(4)));
typedef float    f32x4 __attribute__((ext_vector_type(4)));

__device__ __forceinline__ void async_ld16(const void* g, void* l) {
  __builtin_amdgcn_global_load_lds((const __attribute__((address_space(1))) void*)g,
                                   (__attribute__((address_space(3))) void*)l,
                                   16, 0, 0);
}

// ---------------------------------------------------------------------------
// gemm256: 256x256 output tile, A:[256,lda] rm, B:[256,ldb] rm (B^T layout),
// K % 64 == 0.  512 threads = 8 waves (2M x 4N), wave tile 128x64.
// LDS 128KB double-buffered, XOR-swizzled 16B slots (R10).
// ---------------------------------------------------------------------------
template <typename Epi>
__device__ __forceinline__ void gemm256(f16* lds,
    const f16* __restrict__ A, int lda,
    const f16* __restrict__ B, int ldb,
    int K, Epi&& epi)
{
  const int t    = threadIdx.x;
  const int w    = t >> 6;
  const int lane = t & 63;
  const int q4   = lane >> 4;
  const int l16  = lane & 15;
  const int wm   = w >> 2;      // 0..1
  const int wn   = w & 3;       // 0..3

  f16* ldsA = lds;              // 2 buf x [2 ksub][256][32] f16 (64KB)
  f16* ldsB = lds + 32768;      // same (64KB)

  // staging: lane covers row (lane>>2) of a 16-row group; source 16B chunk is
  // XOR-permuted so the linear LDS dest realizes the swizzled layout.
  const int scx = ((lane & 3) ^ ((lane >> 3) & 3)) * 8;
  const f16* aP = A + (size_t)(lane >> 2) * lda + scx;
  const f16* bP = B + (size_t)(lane >> 2) * ldb + scx;
  const size_t aR0 = (size_t)(w * 32) * lda;        // wave's rowgroup 2w
  const size_t aR1 = aR0 + (size_t)16 * lda;        // rowgroup 2w+1
  const size_t bR0 = (size_t)(w * 32) * ldb;
  const size_t bR1 = bR0 + (size_t)16 * ldb;
  const int wo = w * 1024;      // dest f16 offset of wave's 2 rowgroups (2KB)

  // fragment read bases within a [256][32] ksub section (f16 units), swizzled
  const int sx = (l16 >> 1) & 3;
  const int arow = (wm * 128 + l16) * 32 + ((q4 ^ sx) * 8);
  const int brow = (wn * 64 + l16) * 32 + ((q4 ^ sx) * 8);

  f32x4 acc[8][4];
  const f32x4 vz = {0.f, 0.f, 0.f, 0.f};
#pragma unroll
  for (int i = 0; i < 8; ++i)
#pragma unroll
    for (int j = 0; j < 4; ++j) acc[i][j] = vz;

  // prologue: stage tile 0 in issue order A-k0(2), B-k0(2), A-k1(2), B-k1(2)
  async_ld16(aP + aR0, ldsA + wo);
  async_ld16(aP + aR1, ldsA + wo + 512);
  async_ld16(bP + bR0, ldsB + wo);
  async_ld16(bP + bR1, ldsB + wo + 512);
  asm volatile("" ::: "memory");
  async_ld16(aP + aR0 + 32, ldsA + 8192 + wo);
  async_ld16(aP + aR1 + 32, ldsA + 8192 + wo + 512);
  async_ld16(bP + bR0 + 32, ldsB + 8192 + wo);
  async_ld16(bP + bR1 + 32, ldsB + 8192 + wo + 512);
  asm volatile("s_waitcnt vmcnt(4)" ::: "memory");   // ksub0 of tile 0 landed
  asm volatile("s_barrier" ::: "memory");

  const int NT = K >> 6;
  for (int tk = 0; tk < NT; ++tk) {
    const int d  = (tk & 1) ? 16384 : 0;
    const int dn = 16384 - d;
    const bool st = tk + 1 < NT;
    const int kn = (tk + 1) << 6;
    const f16* aS = ldsA + d;
    const f16* bS = ldsB + d;
    f16x8 a0[4], a1[4], bf[4];

    // ---- phase 1: ksub0 {af0-3, bf0-3} || stage t+1 A-k0 -------------------
#pragma unroll
    for (int i = 0; i < 4; ++i) {
      a0[i] = *(const f16x8*)(aS + arow + i * 512);
      bf[i] = *(const f16x8*)(bS + brow + i * 512);
    }
    if (st) {
      async_ld16(aP + aR0 + kn, ldsA + dn + wo);
      async_ld16(aP + aR1 + kn, ldsA + dn + wo + 512);
    }
    asm volatile("s_barrier" ::: "memory");
    __builtin_amdgcn_s_setprio(1);
#pragma unroll
    for (int mi = 0; mi < 4; ++mi)
#pragma unroll
      for (int ni = 0; ni < 4; ++ni)
        acc[mi][ni] = __builtin_amdgcn_mfma_f32_16x16x32_f16(a0[mi], bf[ni], acc[mi][ni], 0, 0, 0);
    __builtin_amdgcn_s_setprio(0);
    asm volatile("s_barrier" ::: "memory");

    // ---- phase 2: ksub0 {af4-7} || stage t+1 B-k0; vmcnt -> t's ksub1 ------
#pragma unroll
    for (int i = 0; i < 4; ++i)
      a1[i] = *(const f16x8*)(aS + arow + (i + 4) * 512);
    if (st) {
      async_ld16(bP + bR0 + kn, ldsB + dn + wo);
      async_ld16(bP + bR1 + kn, ldsB + dn + wo + 512);
      asm volatile("s_waitcnt vmcnt(4)" ::: "memory");   // t.k1 landed
    } else {
      asm volatile("s_waitcnt vmcnt(0)" ::: "memory");
    }
    asm volatile("s_barrier" ::: "memory");
    __builtin_amdgcn_s_setprio(1);
#pragma unroll
    for (int mi = 0; mi < 4; ++mi)
#pragma unroll
      for (int ni = 0; ni < 4; ++ni)
        acc[mi + 4][ni] = __builtin_amdgcn_mfma_f32_16x16x32_f16(a1[mi], bf[ni], acc[mi + 4][ni], 0, 0, 0);
    __builtin_amdgcn_s_setprio(0);
    asm volatile("s_barrier" ::: "memory");

    // ---- phase 3: ksub1 {af0-3, bf0-3} || stage t+1 A-k1 -------------------
#pragma unroll
    for (int i = 0; i < 4; ++i) {
      a0[i] = *(const f16x8*)(aS + 8192 + arow + i * 512);
      bf[i] = *(const f16x8*)(bS + 8192 + brow + i * 512);
    }
    if (st) {
      async_ld16(aP + aR0 + kn + 32, ldsA + dn + 8192 + wo);
      async_ld16(aP + aR1 + kn + 32, ldsA + dn + 8192 + wo + 512);
    }
    asm volatile("s_barrier" ::: "memory");
    __builtin_amdgcn_s_setprio(1);
#pragma unroll
    for (int mi = 0; mi < 4; ++mi)
#pragma unroll
      for (int ni = 0; ni < 4; ++ni)
        acc[mi][ni] = __builtin_amdgcn_mfma_f32_16x16x32_f16(a0[mi], bf[ni], acc[mi][ni], 0, 0, 0);
    __builtin_amdgcn_s_setprio(0);
    asm volatile("s_barrier" ::: "memory");

    // ---- phase 4: ksub1 {af4-7} || stage t+1 B-k1; vmcnt -> t+1's ksub0 ----
#pragma unroll
    for (int i = 0; i < 4; ++i)
      a1[i] = *(const f16x8*)(aS + 8192 + arow + (i + 4) * 512);
    if (st) {
      async_ld16(bP + bR0 + kn + 32, ldsB + dn + 8192 + wo);
      async_ld16(bP + bR1 + kn + 32, ldsB + dn + 8192 + wo + 512);
      asm volatile("s_waitcnt vmcnt(4)" ::: "memory");   // t+1.k0 landed
    }
    asm volatile("s_barrier" ::: "memory");
    __builtin_amdgcn_s_setprio(1);
#pragma unroll
    for (int mi = 0; mi < 4; ++mi)
#pragma unroll
      for (int ni = 0; ni < 4; ++ni)
        acc[mi + 4][ni] = __builtin_amdgcn_mfma_f32_16x16x32_f16(a1[mi], bf[ni], acc[mi + 4][ni], 0, 0, 0);
    __builtin_amdgcn_s_setprio(0);
    asm volatile("s_barrier" ::: "memory");
  }

  // C/D layout (m89-verified): row = quad*4 + reg, col = lane&15
#pragma unroll
  for (int mi = 0; mi < 8; ++mi)
#pragma unroll
    for (int ni = 0; ni < 4; ++ni)
#pragma unroll
      for (int r = 0; r < 4; ++r)
        epi(wm * 128 + mi * 16 + q4 * 4 + r, wn * 64 + ni * 16 + l16, acc[mi][ni][r]);
}

// ---------------------------------------------------------------------------
// gemm_pipe: 256x128 output tile, A:[256,lda] rm, B:[128,ldb] rm (B^T layout),
// K%64==0, 512 threads = 8 waves (4M x 2N), wave tile 64x64.
// LDS 96KB: A 2buf x 2ksub x [256][32] + B 2buf x 2ksub x [128][32].
// Per K-tile: 2 phases {8 ds_read_b128 | 3 global_load_lds | vmcnt(3) |
// barrier | setprio(1) 16 MFMA setprio(0) | barrier}.  Same XOR swizzle.
// ---------------------------------------------------------------------------
template <typename Epi>
__device__ __forceinline__ void gemm_pipe(f16* lds,
    const f16* __restrict__ A, int lda,
    const f16* __restrict__ B, int ldb,
    int K, Epi&& epi)
{
  const int t    = threadIdx.x;
  const int w    = t >> 6;
  const int lane = t & 63;
  const int q4   = lane >> 4;
  const int l16  = lane & 15;
  const int wm   = w >> 1;
  const int wn   = w & 1;

  // staging: wave w covers rows [w*16, w*16+16); source 16B chunk XOR-permuted
  const int srow = w * 16 + (lane >> 2);
  const int scol = ((lane & 3) ^ ((lane >> 3) & 3)) * 8;
  const f16* aP = A + (size_t)srow * lda + scol;
  const f16* bP = B + (size_t)srow * ldb + scol;
  const size_t a128 = (size_t)128 * lda;
  const int wl = w * 512;             // per-wave 1KB LDS slice (f16 units)

  // fragment read bases within a [rows][32] ksub section (f16 units), swizzled
  const int sx = (l16 >> 1) & 3;
  const int arow = (wm * 64 + l16) * 32 + ((q4 ^ sx) * 8);
  const int brow = (wn * 64 + l16) * 32 + ((q4 ^ sx) * 8);

  f32x4 acc[4][4];
  const f32x4 vz = {0.f, 0.f, 0.f, 0.f};
#pragma unroll
  for (int i = 0; i < 4; ++i)
#pragma unroll
    for (int j = 0; j < 4; ++j) acc[i][j] = vz;

  // ---- prologue: stage tile 0 (k0 then k1); vmcnt(3) -> k0 landed ----------
  async_ld16(aP,             lds + wl);                 // A k0 rows 0-127
  async_ld16(aP + a128,      lds + 4096 + wl);          // A k0 rows 128-255
  async_ld16(bP,             lds + 32768 + wl);         // B k0
  asm volatile("" ::: "memory");
  async_ld16(aP + 32,        lds + 8192 + wl);          // A k1 rows 0-127
  async_ld16(aP + a128 + 32, lds + 8192 + 4096 + wl);   // A k1 rows 128-255
  async_ld16(bP + 32,        lds + 32768 + 4096 + wl);  // B k1
  asm volatile("s_waitcnt vmcnt(3)" ::: "memory");
  asm volatile("s_barrier" ::: "memory");

  const int NT = K >> 6;
  int cb = 0;
  for (int tk = 0; tk < NT; ++tk) {
    f16* aT = lds + cb * 16384;
    f16* bT = lds + 32768 + cb * 8192;
    f16* aD = lds + (cb ^ 1) * 16384;
    f16* bD = lds + 32768 + (cb ^ 1) * 8192;
    const int kn = (tk + 1) << 6;
    const bool st = tk < NT - 1;
#pragma unroll
    for (int s = 0; s < 2; ++s) {
      const f16* aS = aT + s * 8192;
      const f16* bS = bT + s * 4096;
      f16x8 af[4], bf[4];
#pragma unroll
      for (int i = 0; i < 4; ++i) {
        af[i] = *(const f16x8*)(aS + arow + i * 512);
        bf[i] = *(const f16x8*)(bS + brow + i * 512);
      }
      if (st) {
        if (s == 0) {
          async_ld16(aP + kn,        aD + wl);
          async_ld16(aP + a128 + kn, aD + 4096 + wl);
          async_ld16(bP + kn,        bD + wl);
        } else {
          async_ld16(aP + kn + 32,        aD + 8192 + wl);
          async_ld16(aP + a128 + kn + 32, aD + 8192 + 4096 + wl);
          async_ld16(bP + kn + 32,        bD + 4096 + wl);
        }
        asm volatile("s_waitcnt vmcnt(3)" ::: "memory");  // prev phase's 3 landed
      } else if (s == 0) {
        asm volatile("s_waitcnt vmcnt(0)" ::: "memory");  // last tile: k1 landed
      }
      asm volatile("s_barrier" ::: "memory");
      __builtin_amdgcn_s_setprio(1);
#pragma unroll
      for (int mi = 0; mi < 4; ++mi)
#pragma unroll
        for (int ni = 0; ni < 4; ++ni)
          acc[mi][ni] = __builtin_amdgcn_mfma_f32_16x16x32_f16(af[mi], bf[ni], acc[mi][ni], 0, 0, 0);
      __builtin_amdgcn_s_setprio(0);
      asm volatile("s_barrier" ::: "memory");
    }
    cb ^= 1;
  }

  // C/D layout (m89-verified): row = quad*4 + reg, col = lane&15
#pragma unroll
  for (int mi = 0; mi < 4; ++mi)
#pragma unroll
    for (int ni = 0; ni < 4; ++ni)
#pragma unroll
      for (int r = 0; r < 4; ++r)
        epi(wm * 64 + mi * 16 + q4 * 4 + r, wn * 64 + ni * 16 + l16, acc[mi][ni][r]);
}

// ---------------------------------------------------------------------------
// k_qkv5: fused QKV on gemm256.  blocks [0,256): stream0 (16x16 tiles,
// K=2304); [256,384): stream1 (8x16 tiles, K=1024).  N-tiles of 256:
// bx<8 q, 8-11 k, 12-15 v.
// ---------------------------------------------------------------------------
__global__ __launch_bounds__(512, 2) void k_qkv5(
    const f16* __restrict__ xpg, const f16* __restrict__ xex,
    const f16* __restrict__ W0,  const f16* __restrict__ W1,
    f16* __restrict__ q, f16* __restrict__ k, f16* __restrict__ v)
{
  __shared__ alignas(16) f16 lds[65536];
  const int idx = blockIdx.x;
  int by, bx, K; const f16 *A, *B;
  const bool s0 = idx < 256;
  if (s0) { by = idx >> 4; bx = idx & 15; K = 2304;
            A = xpg + (size_t)by * 256 * 2304; B = W0 + (size_t)bx * 256 * 2304; }
  else    { int j = idx - 256; by = j >> 4; bx = j & 15; K = 1024;
            A = xex + (size_t)by * 256 * 1024; B = W1 + (size_t)bx * 256 * 1024; }

  f16* D; int ldd, coff;
  if (bx < 8)       { D = q; ldd = 2048; coff = 0; }
  else if (bx < 12) { D = k; ldd = 1024; coff = 2048; }
  else              { D = v; ldd = 1024; coff = 3072; }
  const int colb = bx * 256 - coff;
  const int rowb = s0 ? ((by >> 2) * 1536 + (by & 3) * 256)
                      : ((by >> 1) * 1536 + 1024 + (by & 1) * 256);

  gemm256(lds, A, K, B, K, K, [&](int r, int c, float fv) {
    D[(size_t)(rowb + r) * ldd + colb + c] = (f16)fv;
  });
}

// ---- post pass: [0,6144) vtrans; [6144,15360) mask->f16; [15360,24576)
// in-place RoPE on pair-interleaved q/k (f16x8 = 4 pairs, float4 cos/sin) ----
__global__ __launch_bounds__(256) void k_post(
    f16* __restrict__ q, f16* __restrict__ k,
    const float* __restrict__ cs, const float* __restrict__ sn,
    const float* __restrict__ msk, f16* __restrict__ mkh,
    const f16* __restrict__ v, f16* __restrict__ vt)
{
  const int blk = blockIdx.x;
  if (blk < 6144) {
    // V transpose: v[B*1536,1024] -> vt[B][4][256][1536]
    __shared__ f16 tile[32][33];
    const int b = blk / 1536, r0 = blk % 1536;
    const int d0 = (r0 & 31) * 32, l0 = (r0 >> 5) * 32;
    const int t = threadIdx.x;
    const int tr = t >> 5, tc = t & 31;
#pragma unroll
    for (int i = 0; i < 4; ++i)
      tile[tr + i * 8][tc] = v[((size_t)b * 1536 + l0 + tr + i * 8) * 1024 + d0 + tc];
    __syncthreads();
#pragma unroll
    for (int i = 0; i < 4; ++i) {
      int d = d0 + tr + i * 8;
      vt[(((size_t)b * 4 + (d >> 8)) * 256 + (d & 255)) * 1536 + l0 + tc] = tile[tc][tr + i * 8];
    }
  } else if (blk < 15360) {
    const size_t gid = ((size_t)(blk - 6144) * 256 + threadIdx.x) * 4;
    float4 m4 = *(const float4*)(msk + gid);
    f16x4 o = {(f16)m4.x, (f16)m4.y, (f16)m4.z, (f16)m4.w};
    *(f16x4*)(mkh + gid) = o;
  } else {
    const size_t tid8 = ((size_t)(blk - 15360) * 256 + threadIdx.x) * 8;
    f16* base; size_t row; int col;
    if (tid8 < 12582912ull) { base = q + tid8; row = tid8 >> 11; col = (int)(tid8 & 2047); }
    else { size_t f = tid8 - 12582912ull; base = k + f; row = f >> 10; col = (int)(f & 1023); }
    const int j0 = (col & 255) >> 1;
    f16x8 x = *(const f16x8*)base;
    float4 c4 = *(const float4*)(cs + row * 128 + j0);
    float4 s4 = *(const float4*)(sn + row * 128 + j0);
    f16x8 o;
    const float cc[4] = {c4.x, c4.y, c4.z, c4.w};
    const float ss[4] = {s4.x, s4.y, s4.z, s4.w};
#pragma unroll
    for (int p = 0; p < 4; ++p) {
      float x1 = (float)x[2 * p], x2 = (float)x[2 * p + 1];
      o[2 * p]     = (f16)(x1 * cc[p] - x2 * ss[p]);
      o[2 * p + 1] = (f16)(x2 * cc[p] + x1 * ss[p]);
    }
    *(f16x8*)base = o;
  }
}

// ---------------------------------------------------------------------------
// k_attn2: unified attention mega-kernel on gemm_pipe (256x128 tiles).
//   blocks [0, nop): oproj batch b_op (72 out0 + 16 out1 = 88)
//   blocks [nop, nop+npv): PV batch b_pv reading Psrc (96)
//   blocks [nop+npv, ...): scores batch b_sc writing f16 Sdst (576)
// ---------------------------------------------------------------------------
__global__ __launch_bounds__(512, 2) void k_attn2(
    const f16* __restrict__ qb, const f16* __restrict__ kb,
    const f16* __restrict__ mask, f16* __restrict__ Sdst,
    const f16* __restrict__ Psrc, const f16* __restrict__ vt,
    f16* __restrict__ att0, f16* __restrict__ att1,
    const f16* __restrict__ wo0, const f16* __restrict__ wo1,
    float* __restrict__ out0, float* __restrict__ out1,
    int b_sc, int b_pv, int b_op, int npv, int nop)
{
  __shared__ alignas(16) f16 lds[49152];
  const int idx = blockIdx.x;
  if (idx < nop) {
    // output projection, K=2048
    int by, bx, ldc, rowb; const f16 *A, *B; float* C;
    if (idx < 72) { by = idx / 18; bx = idx % 18;
                    A = att0 + (size_t)(b_op * 4 + by) * 256 * 2048;
                    B = wo0 + (size_t)bx * 128 * 2048;
                    C = out0; ldc = 2304; rowb = b_op * 1024 + by * 256; }
    else          { int j = idx - 72; by = j >> 3; bx = j & 7;
                    A = att1 + (size_t)(b_op * 2 + by) * 256 * 2048;
                    B = wo1 + (size_t)bx * 128 * 2048;
                    C = out1; ldc = 1024; rowb = b_op * 512 + by * 256; }
    const int colb = bx * 128;
    gemm_pipe(lds, A, 2048, B, 2048, 2048, [&](int r, int c, float fv) {
      C[(size_t)(rowb + r) * ldc + colb + c] = fv;
    });
  } else if (idx < nop + npv) {
    // PV, K=1536
    const int j = idx - nop;
    const int h = j / 12, rem = j % 12, by = rem >> 1, bx = rem & 1;
    const f16* A = Psrc + (size_t)h * 1536 * 1536 + (size_t)by * 256 * 1536;
    const f16* B = vt + (size_t)(b_pv * 4 + (h >> 1)) * 256 * 1536 + (size_t)bx * 128 * 1536;
    f16* dst = (by < 4)
      ? att0 + (size_t)(b_pv * 1024 + by * 256) * 2048 + h * 256 + bx * 128
      : att1 + (size_t)(b_pv * 512 + (by - 4) * 256) * 2048 + h * 256 + bx * 128;
    gemm_pipe(lds, A, 1536, B, 1536, 1536, [&](int r, int c, float fv) {
      dst[(size_t)r * 2048 + c] = (f16)fv;
    });
  } else {
    // scores, K=256
    const int j = idx - nop - npv;
    const int h = j / 72, rem = j % 72, by = rem / 12, bx = rem % 12;
    const f16* A = qb + (size_t)b_sc * 1536 * 2048 + h * 256 + (size_t)by * 256 * 2048;
    const f16* B = kb + (size_t)b_sc * 1536 * 1024 + (h >> 1) * 256 + (size_t)bx * 128 * 1024;
    f16* Sz = Sdst + (size_t)h * 1536 * 1536 + (size_t)by * 256 * 1536 + bx * 128;
    const f16* mb = mask + (size_t)b_sc * 1536 * 1536 + (size_t)by * 256 * 1536 + bx * 128;
    gemm_pipe(lds, A, 2048, B, 1024, 256, [&](int r, int c, float fv) {
      size_t i = (size_t)r * 1536 + c;
      Sz[i] = (f16)(fv * 0.0625f + (float)mb[i]);
    });
  }
}

// ---- wave-per-row softmax over 1536, f16 in/out, in place ------------------
__global__ __launch_bounds__(256) void k_softmax(f16* __restrict__ S)
{
  const int row = blockIdx.x * 4 + (threadIdx.x >> 6);
  const int lane = threadIdx.x & 63;
  f16* p = S + (size_t)row * 1536 + lane * 8;
  f16x8 v0 = *(const f16x8*)p;
  f16x8 v1 = *(const f16x8*)(p + 512);
  f16x8 v2 = *(const f16x8*)(p + 1024);
  float x[24];
#pragma unroll
  for (int i = 0; i < 8; ++i) {
    x[i] = (float)v0[i]; x[8 + i] = (float)v1[i]; x[16 + i] = (float)v2[i];
  }
  float mx = x[0];
#pragma unroll
  for (int i = 1; i < 24; ++i) mx = fmaxf(mx, x[i]);
#pragma unroll
  for (int o = 32; o > 0; o >>= 1) mx = fmaxf(mx, __shfl_xor(mx, o, 64));
  float s = 0.f;
#pragma unroll
  for (int i = 0; i < 24; ++i) { x[i] = __expf(x[i] - mx); s += x[i]; }
#pragma unroll
  for (int o = 32; o > 0; o >>= 1) s += __shfl_xor(s, o, 64);
  const float inv = 1.f / s;
  f16x8 o0, o1, o2;
#pragma unroll
  for (int i = 0; i < 8; ++i) {
    o0[i] = (f16)(x[i] * inv); o1[i] = (f16)(x[8 + i] * inv); o2[i] = (f16)(x[16 + i] * inv);
  }
  *(f16x8*)p = o0; *(f16x8*)(p + 512) = o1; *(f16x8*)(p + 1024) = o2;
}

// ---- flat cast fp32->f16 (pg, ex, Wv0, Wo0, Wv1, Wo1) ----------------------
__global__ __launch_bounds__(256) void k_cast_all(
    const float* __restrict__ s0, const float* __restrict__ s1,
    const float* __restrict__ s2, const float* __restrict__ s3,
    const float* __restrict__ s4, const float* __restrict__ s5,
    f16* __restrict__ ws)
{
  const size_t gid = ((size_t)blockIdx.x * 256 + threadIdx.x) * 4;
  const float* s; size_t off, dst;
  if      (gid < 9437184ull)  { s = s0; off = gid;               dst = 0ull        + off; }
  else if (gid < 11534336ull) { s = s1; off = gid - 9437184ull;  dst = 9437184ull  + off; }
  else if (gid < 13893632ull) { s = s2; off = gid - 11534336ull; dst = 18612224ull + off; }
  else if (gid < 18612224ull) { s = s3; off = gid - 13893632ull; dst = 20971520ull + off; }
  else if (gid < 19660800ull) { s = s4; off = gid - 18612224ull; dst = 28835840ull + off; }
  else                        { s = s5; off = gid - 19660800ull; dst = 29884416ull + off; }
  float4 v = *(const float4*)(s + off);
  f16x4 o = {(f16)v.x, (f16)v.y, (f16)v.z, (f16)v.w};
  *(f16x4*)(ws + dst) = o;
}

// ---- Wq/Wk cast with per-head RoPE pair interleave: dst row h*256+w reads
// src row h*256 + (w>>1) + 128*(w&1).  One block per dst row. ---------------
__global__ __launch_bounds__(256) void k_cast_wr(
    const float* __restrict__ wq0, const float* __restrict__ wk0,
    const float* __restrict__ wq1, const float* __restrict__ wk1,
    f16* __restrict__ W0c, f16* __restrict__ W1c)
{
  const int idx = blockIdx.x;
  const float* src; f16* dstm; int K, r, drow;
  if      (idx < 2048) { src = wq0; dstm = W0c; K = 2304; r = idx;        drow = idx; }
  else if (idx < 3072) { src = wk0; dstm = W0c; K = 2304; r = idx - 2048; drow = idx; }
  else if (idx < 5120) { src = wq1; dstm = W1c; K = 1024; r = idx - 3072; drow = idx - 3072; }
  else                 { src = wk1; dstm = W1c; K = 1024; r = idx - 5120; drow = idx - 3072; }
  const int w = r & 255;
  const int srow = (r & ~255) + (w >> 1) + ((w & 1) << 7);
  const float* sp = src + (size_t)srow * K;
  f16* dp = dstm + (size_t)drow * K;
  for (int c = threadIdx.x * 4; c < K; c += 1024) {
    float4 v = *(const float4*)(sp + c);
    f16x4 o = {(f16)v.x, (f16)v.y, (f16)v.z, (f16)v.w};
    *(f16x4*)(dp + c) = o;
  }
}

// ---------------------------------------------------------------------------
extern "C" void kernel_launch(void* const* d_in, const int* in_sizes, int n_in,
                              void* d_out, int out_size, void* d_ws, size_t ws_size,
                              hipStream_t stream)
{
  (void)in_sizes; (void)n_in; (void)out_size; (void)ws_size;
  const float* pg  = (const float*)d_in[0];
  const float* ex  = (const float*)d_in[1];
  const float* cs  = (const float*)d_in[2];
  const float* sn  = (const float*)d_in[3];
  const float* msk = (const float*)d_in[4];

  char* ws = (char*)d_ws;
  f16* xpg  = (f16*)(ws + 0);           // [4096,2304]   (dead after qkv)
  f16* xex  = (f16*)(ws + 18874368);    // [2048,1024]   (dead after qkv)
  f16* W0c  = (f16*)(ws + 23068672);    // [4096,2304] Wq0i;Wk0i;Wv0 (dead after qkv)
  f16* wo0c = (f16*)(ws + 41943040);    // [2304,2048]
  f16* W1c  = (f16*)(ws + 51380224);    // [4096,1024] Wq1i;Wk1i;Wv1 (dead after qkv)
  f16* wo1c = (f16*)(ws + 59768832);    // [1024,2048]
  f16* qb   = (f16*)(ws + 63963136);    // [B*1536, 2048] f16, pair-interleaved
  f16* kb   = (f16*)(ws + 89128960);    // [B*1536, 1024]
  f16* vb   = (f16*)(ws + 101711872);   // [B*1536, 1024] (dead after post)
  f16* vt   = (f16*)(ws + 114294784);   // [B,4,256,1536]
  f16* att0 = (f16*)(ws + 126877696);   // [B*1024, 2048]
  f16* att1 = (f16*)(ws + 143654912);   // [B*512, 2048]
  f16* S0   = (f16*)(ws + 152043520);   // f16 S/P chunk A: 8*1536*1536
  f16* S1   = (f16*)(ws + 189792256);   // f16 S/P chunk B (ends 227,540,992)
  f16* mkh  = W0c;                      // f16 mask overlays dead W0c (18.9MB)
  float* out0 = (float*)d_out;          // [4,1024,2304]
  float* out1 = out0 + 9437184;         // [4,512,1024]

  // 1) casts
  k_cast_all<<<21248, 256, 0, stream>>>(
      pg, ex, (const float*)d_in[7], (const float*)d_in[8],
      (const float*)d_in[11], (const float*)d_in[12], (f16*)ws);
  k_cast_wr<<<6144, 256, 0, stream>>>(
      (const float*)d_in[5], (const float*)d_in[6],
      (const float*)d_in[9], (const float*)d_in[10], W0c, W1c);

  // 2) fused QKV (both streams) — 256x256-tile 4-fine-phase pipelined GEMM
  k_qkv5<<<384, 512, 0, stream>>>(xpg, xex, W0c, W1c, qb, kb, vb);

  // 3) merged post pass: vtrans + mask->f16 + in-place RoPE
  k_post<<<24576, 256, 0, stream>>>(qb, kb, cs, sn, msk, mkh, vb, vt);

  // 4) attention pipeline (double-buffered f16 S chunks); oproj(b) rides in
  //    the scores(b+2) launch.  Per batch: nop=88, npv=96, nsc=576.
  k_attn2<<<576, 512, 0, stream>>>(qb, kb, mkh, S0, S0, vt, att0, att1, wo0c, wo1c, out0, out1, 0, 0, 0, 0, 0);
  k_softmax<<<3072, 256, 0, stream>>>(S0);
  k_attn2<<<672, 512, 0, stream>>>(qb, kb, mkh, S1, S0, vt, att0, att1, wo0c, wo1c, out0, out1, 1, 0, 0, 96, 0);
  k_softmax<<<3072, 256, 0, stream>>>(S1);
  k_attn2<<<760, 512, 0, stream>>>(qb, kb, mkh, S0, S1, vt, att0, att1, wo0c, wo1c, out0, out1, 2, 1, 0, 96, 88);
  k_softmax<<<3072, 256, 0, stream>>>(S0);
  k_attn2<<<760, 512, 0, stream>>>(qb, kb, mkh, S1, S0, vt, att0, att1, wo0c, wo1c, out0, out1, 3, 2, 1, 96, 88);
  k_softmax<<<3072, 256, 0, stream>>>(S1);

  // 5) tail: PV b3 + oproj b2 (184), then oproj b3 (88)
  k_attn2<<<184, 512, 0, stream>>>(qb, kb, mkh, S0, S1, vt, att0, att1, wo0c, wo1c, out0, out1, 0, 3, 2, 96, 88);
  k_attn2<<<88, 512, 0, stream>>>(qb, kb, mkh, S0, S1, vt, att0, att1, wo0c, wo1c, out0, out1, 0, 0, 3, 0, 88);
}